// Round 18
// baseline (514.681 us; speedup 1.0000x reference)
//
#include <hip/hip_runtime.h>

#define N_ENEMY 4000000
#define N_GUN   1000000
#define N_EDGES 16000000
#define OUTD    8

#define NB   2048      // dst buckets (512 guns each, bucket = dst>>9)
#define GSH  9
#define GPB  512
#define T4   4096      // scatter tile
#define NT4  3907      // ceil(16M/4096)
#define EPT4 16

#define CH   1024      // bucket_v9 chunk (8KB sorted, ~13KB LDS -> 8 blocks/CU)
#define CEPT 4         // CH/256

#define NS   8         // src slices: 512K enemies = 4MB bf16 = one XCD L2
#define SEG_CAP 10240  // slice_sort LDS capacity (mean 8192, +22 sigma)

__device__ __forceinline__ unsigned int rne_bf16(unsigned int u) {
    return (u + 0x7FFFu + ((u >> 16) & 1u)) >> 16;
}
__device__ __forceinline__ unsigned int get_xcc() {
    unsigned int x;
    asm("s_getreg_b32 %0, hwreg(HW_REG_XCC_ID)" : "=s"(x));
    return x;
}

// ---- Fold W_l@W_fc (4x8), W_r@W_fc (8), b_l@W_fc + b_fc (8) into P[48] ----
__global__ void prep_params(const float* __restrict__ W_l, const float* __restrict__ b_l,
                            const float* __restrict__ W_r, const float* __restrict__ W_fc,
                            const float* __restrict__ b_fc, float* __restrict__ P) {
    int o = threadIdx.x;
    if (o < OUTD) {
        float a0 = 0.f, a1 = 0.f, a2 = 0.f, a3 = 0.f, r = 0.f, c = 0.f;
        for (int h = 0; h < 64; ++h) {
            float w = W_fc[h * OUTD + o];
            a0 += W_l[0 * 64 + h] * w;
            a1 += W_l[1 * 64 + h] * w;
            a2 += W_l[2 * 64 + h] * w;
            a3 += W_l[3 * 64 + h] * w;
            r  += W_r[h] * w;
            c  += b_l[h] * w;
        }
        P[0 * OUTD + o] = a0;
        P[1 * OUTD + o] = a1;
        P[2 * OUTD + o] = a2;
        P[3 * OUTD + o] = a3;
        P[4 * OUTD + o] = r;
        P[5 * OUTD + o] = c + b_fc[o];
    }
}

// ---- Convert x_enemy f32x4 -> bf16x4 (packed into uint2) ----
__global__ void conv_kernel(const uint4* __restrict__ xe, uint2* __restrict__ xeb) {
    int i = blockIdx.x * blockDim.x + threadIdx.x;
    if (i >= N_ENEMY) return;
    uint4 v = xe[i];
    uint2 q;
    q.x = rne_bf16(v.x) | (rne_bf16(v.y) << 16);
    q.y = rne_bf16(v.z) | (rne_bf16(v.w) << 16);
    xeb[i] = q;
}

// ---- per-tile dst-bucket histogram (T=4096, bucket = dst>>9) ----
__global__ void hist2_kernel(const int* __restrict__ edst, unsigned short* __restrict__ tileh) {
    __shared__ unsigned int lh[NB];
    int t = threadIdx.x;
    for (int i = t; i < NB; i += 256) lh[i] = 0;
    __syncthreads();
    int ebase = blockIdx.x * T4;
    int nE = N_EDGES - ebase;
    if (nE > T4) nE = T4;
    for (int i = t; i < nE; i += 256)
        atomicAdd(&lh[((unsigned)edst[ebase + i]) >> GSH], 1u);
    __syncthreads();
    unsigned short* row = tileh + (size_t)blockIdx.x * NB;
    for (int i = t; i < NB; i += 256) row[i] = (unsigned short)lh[i];
}

// ---- per-bucket exclusive prefix over tiles (in-place) + totals ----
template<int K>
__global__ __launch_bounds__(256)
void tile_scanT(unsigned short* __restrict__ tileh, unsigned int* __restrict__ tot,
                int nbk, int ntile) {
    __shared__ unsigned int part[256][17];
    int t = threadIdx.x;
    int b0 = blockIdx.x * 16;
    unsigned int loc[16];
#pragma unroll
    for (int j = 0; j < 16; ++j) loc[j] = 0;
    for (int k = 0; k < K; ++k) {
        int tile = t * K + k;
        if (tile < ntile) {
            const unsigned short* row = tileh + (size_t)tile * nbk + b0;
#pragma unroll
            for (int j = 0; j < 16; ++j) loc[j] += row[j];
        }
    }
#pragma unroll
    for (int j = 0; j < 16; ++j) part[t][j] = loc[j];
    __syncthreads();
    if (t < 16) {
        unsigned int acc = 0;
        for (int i = 0; i < 256; ++i) {
            unsigned int v = part[i][t];
            part[i][t] = acc;
            acc += v;
        }
        tot[b0 + t] = acc;
    }
    __syncthreads();
    unsigned int run[16];
#pragma unroll
    for (int j = 0; j < 16; ++j) run[j] = part[t][j];
    for (int k = 0; k < K; ++k) {
        int tile = t * K + k;
        if (tile < ntile) {
            unsigned short* row = tileh + (size_t)tile * nbk + b0;
#pragma unroll
            for (int j = 0; j < 16; ++j) {
                unsigned int c = row[j];
                row[j] = (unsigned short)run[j];
                run[j] += c;
            }
        }
    }
}

// ---- exclusive scan of 2048 totals (proven round-9 kernel) ----
__global__ void scan2048(const unsigned int* __restrict__ tot,
                         unsigned int* __restrict__ offs) {
    __shared__ unsigned int tmp[1024];
    int t = threadIdx.x;
    unsigned int a = tot[2 * t], b = tot[2 * t + 1];
    unsigned int p = a + b;
    tmp[t] = p;
    __syncthreads();
    for (int d = 1; d < 1024; d <<= 1) {
        unsigned int v = (t >= d) ? tmp[t - d] : 0u;
        __syncthreads();
        tmp[t] += v;
        __syncthreads();
    }
    unsigned int excl = tmp[t] - p;
    offs[2 * t] = excl;
    offs[2 * t + 1] = excl + a;
    if (t == 1023) offs[2048] = tmp[t];
}

// ---- tile-sorted partition by dst bucket (T=4096, NB=2048) ----
// payload word: (src << 9) | g   where g = dst & 511  (src < 2^22 -> 31 bits)
__global__ __launch_bounds__(256, 3)
void scatter_sorted(const int* __restrict__ esrc, const int* __restrict__ edst,
                    const unsigned int* __restrict__ offsets,
                    const unsigned short* __restrict__ tileh,
                    unsigned int* __restrict__ payload) {
    __shared__ unsigned int cnt[NB];
    __shared__ unsigned int base[NB];
    __shared__ unsigned int gb[NB];
    __shared__ unsigned short bOf[T4];
    __shared__ unsigned int sorted[T4];
    __shared__ unsigned int partial[256];
    int t = threadIdx.x;
    int tile = blockIdx.x;
    int ebase = tile * T4;
    int nE = N_EDGES - ebase;
    if (nE > T4) nE = T4;
    for (int i = t; i < NB; i += 256) cnt[i] = 0;
    __syncthreads();
    unsigned int w[EPT4];
    unsigned int br[EPT4];
#pragma unroll
    for (int k = 0; k < EPT4; ++k) {
        int idx = k * 256 + t;
        if (idx < nE) {
            unsigned int s = (unsigned int)esrc[ebase + idx];
            unsigned int d = (unsigned int)edst[ebase + idx];
            unsigned int b = d >> GSH;
            unsigned int g = d & (GPB - 1u);
            unsigned int r = atomicAdd(&cnt[b], 1u);
            w[k]  = (s << GSH) | g;
            br[k] = (b << 13) | r;
        } else br[k] = 0xFFFFFFFFu;
    }
    __syncthreads();
    unsigned int loc[8];
    unsigned int s = 0;
#pragma unroll
    for (int j = 0; j < 8; ++j) {
        int b = t * 8 + j;
        unsigned int c = cnt[b];
        loc[j] = s; s += c;
    }
    partial[t] = s;
    __syncthreads();
    for (int d = 1; d < 256; d <<= 1) {
        unsigned int v = (t >= d) ? partial[t - d] : 0u;
        __syncthreads();
        partial[t] += v;
        __syncthreads();
    }
    unsigned int excl = (t > 0) ? partial[t - 1] : 0u;
#pragma unroll
    for (int j = 0; j < 8; ++j) base[t * 8 + j] = excl + loc[j];
    __syncthreads();
    const unsigned short* trow = tileh + (size_t)tile * NB;
#pragma unroll
    for (int j = 0; j < 8; ++j) {
        int b = t * 8 + j;
        gb[b] = offsets[b] + (unsigned int)trow[b];
        unsigned int bs = base[b];
        unsigned int c = cnt[b];
        for (unsigned int p = bs; p < bs + c; ++p) bOf[p] = (unsigned short)b;
    }
    __syncthreads();
#pragma unroll
    for (int k = 0; k < EPT4; ++k) {
        if (br[k] != 0xFFFFFFFFu) {
            unsigned int b = br[k] >> 13;
            unsigned int r = br[k] & 8191u;
            sorted[base[b] + r] = w[k];
        }
    }
    __syncthreads();
    for (int p = t; p < nE; p += 256) {
        unsigned int b = bOf[p];
        payload[gb[b] + ((unsigned int)p - base[b])] = sorted[p];
    }
}

// ---- per-bucket counting sort by src-slice (slice = p>>28, 8 bins) — proven algo ----
__global__ __launch_bounds__(256)
void slice_sort(const unsigned int* __restrict__ offsets,
                unsigned int* __restrict__ payload,
                unsigned int* __restrict__ stab) {
    __shared__ unsigned int A[SEG_CAP];
    __shared__ unsigned int cnt[NS];
    __shared__ unsigned int base[NS + 1];
    int b = blockIdx.x;
    int t = threadIdx.x;
    unsigned int segS = offsets[b];
    unsigned int segE = offsets[b + 1];
    unsigned int len = segE - segS;
    if (len > SEG_CAP) {
        if (t <= NS) stab[b * (NS + 1) + t] = (t == 0) ? segS : segE;
        return;
    }
    if (t < NS) cnt[t] = 0;
    __syncthreads();
    for (unsigned int i = t; i < len; i += 256) {
        unsigned int w = payload[segS + i];
        A[i] = w;
        atomicAdd(&cnt[w >> 28], 1u);
    }
    __syncthreads();
    if (t == 0) {
        unsigned int acc = 0;
        for (int k = 0; k < NS; ++k) { base[k] = acc; acc += cnt[k]; }
        base[NS] = acc;
    }
    __syncthreads();
    if (t < NS) cnt[t] = 0;
    __syncthreads();
    for (unsigned int i = t; i < len; i += 256) {
        unsigned int w = A[i];
        unsigned int k = w >> 28;
        unsigned int r = atomicAdd(&cnt[k], 1u);
        payload[segS + base[k] + r] = w;
    }
    if (t <= NS) stab[b * (NS + 1) + t] = segS + base[t];
}

// ---- bucket_v9: slice-rotated walk, 1 LDS atomic/edge, 512 guns/block ----
__global__ __launch_bounds__(256)
void bucket_v9(const unsigned int* __restrict__ stab,
               const unsigned int* __restrict__ payload,
               const uint2* __restrict__ xeb,
               const float* __restrict__ xg,
               const float* __restrict__ P,
               float* __restrict__ out) {
    __shared__ unsigned long long sorted[CH];   // 8 KB
    __shared__ unsigned int cnt[GPB];
    __shared__ unsigned int base_[GPB];
    __shared__ unsigned int partial[256];
    __shared__ float sP[48];
    int t = threadIdx.x;
    if (t < 48) sP[t] = P[t];
    __syncthreads();

    // per-thread accumulators: guns 2t, 2t+1
    float a0[2] = {0,0}, a1[2] = {0,0}, a2[2] = {0,0}, a3[2] = {0,0};
    float an[2] = {0,0};

    unsigned int b = blockIdx.x;
    unsigned int rot = get_xcc() & (NS - 1u);

    for (int si = 0; si < NS; ++si) {
        unsigned int s = ((unsigned int)si + rot) & (NS - 1u);
        unsigned int rs = stab[b * (NS + 1) + s];
        unsigned int re = stab[b * (NS + 1) + s + 1];

        for (unsigned int cs = rs; cs < re; cs += CH) {
            int n = (int)((re - cs < (unsigned int)CH) ? (re - cs) : (unsigned int)CH);
            for (int i = t; i < GPB; i += 256) cnt[i] = 0;
            __syncthreads();

            unsigned int g_[CEPT], r_[CEPT];
            uint2 q_[CEPT];
#pragma unroll
            for (int k = 0; k < CEPT; ++k) {
                int idx = k * 256 + t;
                if (idx < n) {
                    unsigned int p = payload[cs + idx];
                    q_[k] = xeb[p >> GSH];
                    unsigned int g = p & (GPB - 1u);
                    g_[k] = g;
                    r_[k] = atomicAdd(&cnt[g], 1u);   // ONE atomic: rank AND hist
                } else g_[k] = 0xFFFFFFFFu;
            }
            __syncthreads();

            unsigned int myc[2];
            unsigned int loc[2];
            unsigned int acc = 0;
#pragma unroll
            for (int j = 0; j < 2; ++j) {
                myc[j] = cnt[t * 2 + j];
                loc[j] = acc; acc += myc[j];
            }
            partial[t] = acc;
            __syncthreads();
            for (int d = 1; d < 256; d <<= 1) {
                unsigned int v = (t >= d) ? partial[t - d] : 0u;
                __syncthreads();
                partial[t] += v;
                __syncthreads();
            }
            unsigned int excl = (t > 0) ? partial[t - 1] : 0u;
            unsigned int myb[2];
#pragma unroll
            for (int j = 0; j < 2; ++j) {
                myb[j] = excl + loc[j];
                base_[t * 2 + j] = myb[j];
            }
            __syncthreads();

#pragma unroll
            for (int k = 0; k < CEPT; ++k) {
                if (g_[k] != 0xFFFFFFFFu) {
                    sorted[base_[g_[k]] + r_[k]] =
                        ((unsigned long long)q_[k].y << 32) | (unsigned long long)q_[k].x;
                }
            }
            __syncthreads();

#pragma unroll
            for (int j = 0; j < 2; ++j) {
                unsigned int bs = myb[j], c = myc[j];
                for (unsigned int p2 = bs; p2 < bs + c; ++p2) {
                    unsigned long long v = sorted[p2];
                    unsigned int lo = (unsigned int)v, hi = (unsigned int)(v >> 32);
                    a0[j] += __uint_as_float(lo << 16);
                    a1[j] += __uint_as_float(lo & 0xffff0000u);
                    a2[j] += __uint_as_float(hi << 16);
                    a3[j] += __uint_as_float(hi & 0xffff0000u);
                }
                an[j] += (float)c;
            }
            __syncthreads();
        }
    }

    // epilogue: guns 2t, 2t+1, non-atomic, direct to out
#pragma unroll
    for (int j = 0; j < 2; ++j) {
        int g = t * 2 + j;
        unsigned int G = (b << GSH) + (unsigned int)g;
        if (G >= N_GUN) continue;
        float inv = 1.0f / fmaxf(an[j], 1.0f);
        float m0 = a0[j] * inv, m1 = a1[j] * inv, m2 = a2[j] * inv, m3 = a3[j] * inv;
        float xv = xg[G];
        float res[OUTD];
#pragma unroll
        for (int o = 0; o < OUTD; ++o) {
            res[o] = m0 * sP[o] + m1 * sP[8 + o] + m2 * sP[16 + o] + m3 * sP[24 + o]
                   + xv * sP[32 + o] + sP[40 + o];
        }
        float4* op = (float4*)(out + (size_t)G * OUTD);
        op[0] = make_float4(res[0], res[1], res[2], res[3]);
        op[1] = make_float4(res[4], res[5], res[6], res[7]);
    }
}

// ================= atomic fallback (tiny ws) =================================
__global__ void edge_kernel(const int4* __restrict__ esrc4, const int4* __restrict__ edst4,
                            const float4* __restrict__ xe, float* __restrict__ summed,
                            float* __restrict__ counts) {
    int t = blockIdx.x * blockDim.x + threadIdx.x;
    if (t >= N_EDGES / 4) return;
    int4 s4 = esrc4[t];
    int4 d4 = edst4[t];
    int ss[4] = { s4.x, s4.y, s4.z, s4.w };
    int dd[4] = { d4.x, d4.y, d4.z, d4.w };
#pragma unroll
    for (int k = 0; k < 4; ++k) {
        float4 m = xe[ss[k]];
        float* basep = summed + (size_t)dd[k] * 4;
        atomicAdd(basep + 0, m.x);
        atomicAdd(basep + 1, m.y);
        atomicAdd(basep + 2, m.z);
        atomicAdd(basep + 3, m.w);
        atomicAdd(counts + dd[k], 1.0f);
    }
}

__global__ void gun_kernel(const float4* __restrict__ summed, const float* __restrict__ counts,
                           const float* __restrict__ xg, const float* __restrict__ P,
                           float* __restrict__ out) {
    __shared__ float sP[48];
    if (threadIdx.x < 48) sP[threadIdx.x] = P[threadIdx.x];
    __syncthreads();
    int g = blockIdx.x * blockDim.x + threadIdx.x;
    if (g >= N_GUN) return;
    float4 s = summed[g];
    float cnt = counts[g];
    float inv = 1.0f / fmaxf(cnt, 1.0f);
    float m0 = s.x * inv, m1 = s.y * inv, m2 = s.z * inv, m3 = s.w * inv;
    float xv = xg[g];
    float res[OUTD];
#pragma unroll
    for (int o = 0; o < OUTD; ++o) {
        res[o] = m0 * sP[o] + m1 * sP[8 + o] + m2 * sP[16 + o] + m3 * sP[24 + o]
               + xv * sP[32 + o] + sP[40 + o];
    }
    float4* op = (float4*)(out + (size_t)g * OUTD);
    op[0] = make_float4(res[0], res[1], res[2], res[3]);
    op[1] = make_float4(res[4], res[5], res[6], res[7]);
}

extern "C" void kernel_launch(void* const* d_in, const int* in_sizes, int n_in,
                              void* d_out, int out_size, void* d_ws, size_t ws_size,
                              hipStream_t stream) {
    const float* x_enemy = (const float*)d_in[0];
    const float* x_gun   = (const float*)d_in[1];
    const int*   esrc    = (const int*)d_in[2];
    const int*   edst    = (const int*)d_in[3];
    const float* W_l     = (const float*)d_in[4];
    const float* b_l     = (const float*)d_in[5];
    const float* W_r     = (const float*)d_in[6];
    const float* W_fc    = (const float*)d_in[7];
    const float* b_fc    = (const float*)d_in[8];
    float* out = (float*)d_out;

    // ws layout (u32 units). tileh (u16, [3907][2048] = 16MB) aliases the xeb
    // region (32MB): tileh is consumed by scatter_sorted; conv_kernel runs after.
    const size_t PAYLOAD_OFF = 0;                            // 16M u32 = 64 MB
    const size_t XEB_OFF     = (size_t)N_EDGES;              // 8M u32 = 32 MB
    const size_t TOT_OFF     = XEB_OFF + (size_t)N_ENEMY*2;  // +2048
    const size_t OFFS_OFF    = TOT_OFF + NB;                 // +2049
    const size_t P_OFF       = OFFS_OFF + NB + 1;            // +48
    const size_t STAB_OFF    = P_OFF + 48;                   // +NB*(NS+1)
    const size_t NEEDED_FULL = (STAB_OFF + (size_t)NB * (NS + 1) + 16) * sizeof(unsigned int);

    if (ws_size >= NEEDED_FULL) {
        unsigned int*   ws      = (unsigned int*)d_ws;
        unsigned int*   payload = ws + PAYLOAD_OFF;
        uint2*          xeb     = (uint2*)(ws + XEB_OFF);
        unsigned short* tileh   = (unsigned short*)(ws + XEB_OFF);  // alias, dead before conv
        unsigned int*   tot     = ws + TOT_OFF;
        unsigned int*   offsets = ws + OFFS_OFF;
        float*          P       = (float*)(ws + P_OFF);
        unsigned int*   stab    = ws + STAB_OFF;

        prep_params<<<1, 64, 0, stream>>>(W_l, b_l, W_r, W_fc, b_fc, P);
        hist2_kernel<<<NT4, 256, 0, stream>>>(edst, tileh);
        tile_scanT<16><<<NB / 16, 256, 0, stream>>>(tileh, tot, NB, NT4);
        scan2048<<<1, 1024, 0, stream>>>(tot, offsets);
        scatter_sorted<<<NT4, 256, 0, stream>>>(esrc, edst, offsets, tileh, payload);
        slice_sort<<<NB, 256, 0, stream>>>(offsets, payload, stab);
        conv_kernel<<<(N_ENEMY + 255) / 256, 256, 0, stream>>>((const uint4*)x_enemy, xeb);
        bucket_v9<<<NB, 256, 0, stream>>>(stab, payload, xeb, x_gun, P, out);
    } else {
        float* summed = (float*)d_ws;
        float* counts = summed + (size_t)N_GUN * 4;
        float* P      = counts + N_GUN;
        hipMemsetAsync(d_ws, 0, ((size_t)N_GUN * 5 + 48) * sizeof(float), stream);
        prep_params<<<1, 64, 0, stream>>>(W_l, b_l, W_r, W_fc, b_fc, P);
        int edge_threads = N_EDGES / 4;
        edge_kernel<<<(edge_threads + 255) / 256, 256, 0, stream>>>(
            (const int4*)esrc, (const int4*)edst, (const float4*)x_enemy, summed, counts);
        gun_kernel<<<(N_GUN + 255) / 256, 256, 0, stream>>>(
            (const float4*)summed, counts, x_gun, P, out);
    }
}

// Round 20
// 461.801 us; speedup vs baseline: 1.1145x; 1.1145x over previous
//
#include <hip/hip_runtime.h>

#define N_ENEMY 4000000
#define N_GUN   1000000
#define N_EDGES 16000000
#define OUTD    8

#define NB   1024      // dst buckets
#define GPB  977       // guns per bucket
#define T4   4096      // scatter tile
#define NT4  3907      // ceil(16M/4096)
#define EPT4 16

#define CH   1024      // bucket chunk (8KB sorted -> ~17.9KB LDS -> 8 blocks/CU)
#define CEPT 4         // CH/256

#define NS   8         // src slices: 512K enemies = 4MB bf16 = one XCD L2
#define SEG_CAP 16128  // slice_sort LDS capacity

// exact floor(dst/977) for dst <= 1M
__device__ __forceinline__ unsigned int bucket_of(unsigned int dst) {
    return (unsigned int)(((unsigned long long)dst * 1125395730ull) >> 40);
}
__device__ __forceinline__ unsigned int rne_bf16(unsigned int u) {
    return (u + 0x7FFFu + ((u >> 16) & 1u)) >> 16;
}
__device__ __forceinline__ unsigned int get_xcc() {
    unsigned int x;
    asm("s_getreg_b32 %0, hwreg(HW_REG_XCC_ID)" : "=s"(x));
    return x;
}

// ---- Fold W_l@W_fc (4x8), W_r@W_fc (8), b_l@W_fc + b_fc (8) into P[48] ----
__global__ void prep_params(const float* __restrict__ W_l, const float* __restrict__ b_l,
                            const float* __restrict__ W_r, const float* __restrict__ W_fc,
                            const float* __restrict__ b_fc, float* __restrict__ P) {
    int o = threadIdx.x;
    if (o < OUTD) {
        float a0 = 0.f, a1 = 0.f, a2 = 0.f, a3 = 0.f, r = 0.f, c = 0.f;
        for (int h = 0; h < 64; ++h) {
            float w = W_fc[h * OUTD + o];
            a0 += W_l[0 * 64 + h] * w;
            a1 += W_l[1 * 64 + h] * w;
            a2 += W_l[2 * 64 + h] * w;
            a3 += W_l[3 * 64 + h] * w;
            r  += W_r[h] * w;
            c  += b_l[h] * w;
        }
        P[0 * OUTD + o] = a0;
        P[1 * OUTD + o] = a1;
        P[2 * OUTD + o] = a2;
        P[3 * OUTD + o] = a3;
        P[4 * OUTD + o] = r;
        P[5 * OUTD + o] = c + b_fc[o];
    }
}

// ---- Convert x_enemy f32x4 -> bf16x4 (packed into uint2) ----
__global__ void conv_kernel(const uint4* __restrict__ xe, uint2* __restrict__ xeb) {
    int i = blockIdx.x * blockDim.x + threadIdx.x;
    if (i >= N_ENEMY) return;
    uint4 v = xe[i];
    uint2 q;
    q.x = rne_bf16(v.x) | (rne_bf16(v.y) << 16);
    q.y = rne_bf16(v.z) | (rne_bf16(v.w) << 16);
    xeb[i] = q;
}

// ---- per-tile dst-bucket histogram (T=4096) ----
__global__ void hist2_kernel(const int* __restrict__ edst, unsigned short* __restrict__ tileh) {
    __shared__ unsigned int lh[NB];
    int t = threadIdx.x;
    for (int i = t; i < NB; i += 256) lh[i] = 0;
    __syncthreads();
    int ebase = blockIdx.x * T4;
    int nE = N_EDGES - ebase;
    if (nE > T4) nE = T4;
    for (int i = t; i < nE; i += 256)
        atomicAdd(&lh[bucket_of((unsigned)edst[ebase + i])], 1u);
    __syncthreads();
    unsigned short* row = tileh + (size_t)blockIdx.x * NB;
    for (int i = t; i < NB; i += 256) row[i] = (unsigned short)lh[i];
}

// ---- per-bucket exclusive prefix over tiles (in-place) + totals ----
template<int K>
__global__ __launch_bounds__(256)
void tile_scanT(unsigned short* __restrict__ tileh, unsigned int* __restrict__ tot,
                int nbk, int ntile) {
    __shared__ unsigned int part[256][17];
    int t = threadIdx.x;
    int b0 = blockIdx.x * 16;
    unsigned int loc[16];
#pragma unroll
    for (int j = 0; j < 16; ++j) loc[j] = 0;
    for (int k = 0; k < K; ++k) {
        int tile = t * K + k;
        if (tile < ntile) {
            const unsigned short* row = tileh + (size_t)tile * nbk + b0;
#pragma unroll
            for (int j = 0; j < 16; ++j) loc[j] += row[j];
        }
    }
#pragma unroll
    for (int j = 0; j < 16; ++j) part[t][j] = loc[j];
    __syncthreads();
    if (t < 16) {
        unsigned int acc = 0;
        for (int i = 0; i < 256; ++i) {
            unsigned int v = part[i][t];
            part[i][t] = acc;
            acc += v;
        }
        tot[b0 + t] = acc;
    }
    __syncthreads();
    unsigned int run[16];
#pragma unroll
    for (int j = 0; j < 16; ++j) run[j] = part[t][j];
    for (int k = 0; k < K; ++k) {
        int tile = t * K + k;
        if (tile < ntile) {
            unsigned short* row = tileh + (size_t)tile * nbk + b0;
#pragma unroll
            for (int j = 0; j < 16; ++j) {
                unsigned int c = row[j];
                row[j] = (unsigned short)run[j];
                run[j] += c;
            }
        }
    }
}

__global__ void scan_kernel(const unsigned int* __restrict__ tot,
                            unsigned int* __restrict__ offsets) {
    __shared__ unsigned int tmp[1024];
    int t = threadIdx.x;
    unsigned int v0 = (t < NB) ? tot[t] : 0u;
    tmp[t] = v0;
    __syncthreads();
    for (int d = 1; d < 1024; d <<= 1) {
        unsigned int v = (t >= d) ? tmp[t - d] : 0u;
        __syncthreads();
        tmp[t] += v;
        __syncthreads();
    }
    if (t < NB) offsets[t] = tmp[t] - v0;
    if (t == NB - 1) offsets[NB] = tmp[t];
}

// ---- tile-sorted partition by dst bucket (T=4096, 4 blocks/CU) ----
__global__ __launch_bounds__(256, 4)
void scatter_sorted(const int* __restrict__ esrc, const int* __restrict__ edst,
                    const unsigned int* __restrict__ offsets,
                    const unsigned short* __restrict__ tileh,
                    unsigned int* __restrict__ payload) {
    __shared__ unsigned int cnt[NB];
    __shared__ unsigned int base[NB];
    __shared__ unsigned int gb[NB];
    __shared__ unsigned short bOf[T4];
    __shared__ unsigned int sorted[T4];
    __shared__ unsigned int partial[256];
    int t = threadIdx.x;
    int tile = blockIdx.x;
    int ebase = tile * T4;
    int nE = N_EDGES - ebase;
    if (nE > T4) nE = T4;
    for (int i = t; i < NB; i += 256) cnt[i] = 0;
    __syncthreads();
    unsigned int w[EPT4];
    unsigned int br[EPT4];
#pragma unroll
    for (int k = 0; k < EPT4; ++k) {
        int idx = k * 256 + t;
        if (idx < nE) {
            unsigned int s = (unsigned int)esrc[ebase + idx];
            unsigned int d = (unsigned int)edst[ebase + idx];
            unsigned int b = bucket_of(d);
            unsigned int g = d - b * GPB;
            unsigned int r = atomicAdd(&cnt[b], 1u);
            w[k]  = (s << 10) | g;
            br[k] = (b << 13) | r;
        } else br[k] = 0xFFFFFFFFu;
    }
    __syncthreads();
    unsigned int loc[4];
    unsigned int s = 0;
#pragma unroll
    for (int j = 0; j < 4; ++j) {
        int b = t * 4 + j;
        unsigned int c = cnt[b];
        loc[j] = s; s += c;
    }
    partial[t] = s;
    __syncthreads();
    for (int d = 1; d < 256; d <<= 1) {
        unsigned int v = (t >= d) ? partial[t - d] : 0u;
        __syncthreads();
        partial[t] += v;
        __syncthreads();
    }
    unsigned int excl = (t > 0) ? partial[t - 1] : 0u;
#pragma unroll
    for (int j = 0; j < 4; ++j) base[t * 4 + j] = excl + loc[j];
    __syncthreads();
    const unsigned short* trow = tileh + (size_t)tile * NB;
#pragma unroll
    for (int j = 0; j < 4; ++j) {
        int b = t * 4 + j;
        gb[b] = offsets[b] + (unsigned int)trow[b];
        unsigned int bs = base[b];
        unsigned int c = cnt[b];
        for (unsigned int p = bs; p < bs + c; ++p) bOf[p] = (unsigned short)b;
    }
    __syncthreads();
#pragma unroll
    for (int k = 0; k < EPT4; ++k) {
        if (br[k] != 0xFFFFFFFFu) {
            unsigned int b = br[k] >> 13;
            unsigned int r = br[k] & 8191u;
            sorted[base[b] + r] = w[k];
        }
    }
    __syncthreads();
    for (int p = t; p < nE; p += 256) {
        unsigned int b = bOf[p];
        payload[gb[b] + ((unsigned int)p - base[b])] = sorted[p];
    }
}

// ---- per-bucket counting sort by src-slice (slice = w>>29, 8 bins) — proven ----
__global__ __launch_bounds__(256)
void slice_sort(const unsigned int* __restrict__ offsets,
                unsigned int* __restrict__ payload,
                unsigned int* __restrict__ stab) {
    __shared__ unsigned int A[SEG_CAP];
    __shared__ unsigned int cnt[NS];
    __shared__ unsigned int base[NS + 1];
    int b = blockIdx.x;
    int t = threadIdx.x;
    unsigned int segS = offsets[b];
    unsigned int segE = offsets[b + 1];
    unsigned int len = segE - segS;
    if (len > SEG_CAP) {
        if (t <= NS) stab[b * (NS + 1) + t] = (t == 0) ? segS : segE;
        return;
    }
    if (t < NS) cnt[t] = 0;
    __syncthreads();
    for (unsigned int i = t; i < len; i += 256) {
        unsigned int w = payload[segS + i];
        A[i] = w;
        atomicAdd(&cnt[w >> 29], 1u);
    }
    __syncthreads();
    if (t == 0) {
        unsigned int acc = 0;
        for (int k = 0; k < NS; ++k) { base[k] = acc; acc += cnt[k]; }
        base[NS] = acc;
    }
    __syncthreads();
    if (t < NS) cnt[t] = 0;
    __syncthreads();
    for (unsigned int i = t; i < len; i += 256) {
        unsigned int w = A[i];
        unsigned int k = w >> 29;
        unsigned int r = atomicAdd(&cnt[k], 1u);
        payload[segS + base[k] + r] = w;
    }
    if (t <= NS) stab[b * (NS + 1) + t] = segS + base[t];
}

// ---- bucket_v9s: CHUNK-PARITY split (2 blocks/bucket), rot-independent partition ----
__global__ __launch_bounds__(256)
void bucket_v9s(const unsigned int* __restrict__ stab,
                const unsigned int* __restrict__ payload,
                const uint2* __restrict__ xeb,
                unsigned long long* __restrict__ sumP,
                unsigned short* __restrict__ cntP) {
    __shared__ unsigned long long sorted[CH];   // 8 KB
    __shared__ unsigned int cnt[1024];
    __shared__ unsigned int base_[1024];
    __shared__ unsigned int partial[256];
    int t = threadIdx.x;

    float a0[4] = {0,0,0,0}, a1[4] = {0,0,0,0}, a2[4] = {0,0,0,0}, a3[4] = {0,0,0,0};
    float an[4] = {0,0,0,0};

    unsigned int b    = (unsigned int)blockIdx.x >> 1;
    unsigned int half = (unsigned int)blockIdx.x & 1u;
    unsigned int rot = get_xcc() & (NS - 1u);   // order-only; partition is rot-independent

    for (int si = 0; si < NS; ++si) {
        unsigned int s = ((unsigned int)si + rot) & (NS - 1u);
        unsigned int rs = stab[b * (NS + 1) + s];
        unsigned int re = stab[b * (NS + 1) + s + 1];

        // chunk-parity split: half h takes chunks h, h+2, h+4, ... of this slice
        for (unsigned int cs = rs + half * CH; cs < re; cs += 2u * CH) {
            int n = (int)((re - cs < (unsigned int)CH) ? (re - cs) : (unsigned int)CH);
            for (int i = t; i < 1024; i += 256) cnt[i] = 0;
            __syncthreads();

            unsigned int g_[CEPT], r_[CEPT];
            uint2 q_[CEPT];
#pragma unroll
            for (int k = 0; k < CEPT; ++k) {
                int idx = k * 256 + t;
                if (idx < n) {
                    unsigned int p = payload[cs + idx];
                    q_[k] = xeb[p >> 10];
                    unsigned int g = p & 1023u;
                    g_[k] = g;
                    r_[k] = atomicAdd(&cnt[g], 1u);   // ONE atomic: rank AND hist
                } else g_[k] = 0xFFFFFFFFu;
            }
            __syncthreads();

            unsigned int myc[4];
            unsigned int loc[4];
            unsigned int acc = 0;
#pragma unroll
            for (int j = 0; j < 4; ++j) {
                myc[j] = cnt[t * 4 + j];
                loc[j] = acc; acc += myc[j];
            }
            partial[t] = acc;
            __syncthreads();
            for (int d = 1; d < 256; d <<= 1) {
                unsigned int v = (t >= d) ? partial[t - d] : 0u;
                __syncthreads();
                partial[t] += v;
                __syncthreads();
            }
            unsigned int excl = (t > 0) ? partial[t - 1] : 0u;
            unsigned int myb[4];
#pragma unroll
            for (int j = 0; j < 4; ++j) {
                myb[j] = excl + loc[j];
                base_[t * 4 + j] = myb[j];
            }
            __syncthreads();

#pragma unroll
            for (int k = 0; k < CEPT; ++k) {
                if (g_[k] != 0xFFFFFFFFu) {
                    sorted[base_[g_[k]] + r_[k]] =
                        ((unsigned long long)q_[k].y << 32) | (unsigned long long)q_[k].x;
                }
            }
            __syncthreads();

#pragma unroll
            for (int j = 0; j < 4; ++j) {
                unsigned int bs = myb[j], c = myc[j];
                for (unsigned int p2 = bs; p2 < bs + c; ++p2) {
                    unsigned long long v = sorted[p2];
                    unsigned int lo = (unsigned int)v, hi = (unsigned int)(v >> 32);
                    a0[j] += __uint_as_float(lo << 16);
                    a1[j] += __uint_as_float(lo & 0xffff0000u);
                    a2[j] += __uint_as_float(hi << 16);
                    a3[j] += __uint_as_float(hi & 0xffff0000u);
                }
                an[j] += (float)c;
            }
            __syncthreads();
        }
    }

    // write bf16x4-packed partial + u16 count (round-11-proven format)
    size_t pb = (size_t)blockIdx.x * GPB;
#pragma unroll
    for (int j = 0; j < 4; ++j) {
        int g = t * 4 + j;
        if (g >= GPB) continue;
        unsigned long long lo = (unsigned long long)(rne_bf16(__float_as_uint(a0[j])) |
                                                    (rne_bf16(__float_as_uint(a1[j])) << 16));
        unsigned long long hi = (unsigned long long)(rne_bf16(__float_as_uint(a2[j])) |
                                                    (rne_bf16(__float_as_uint(a3[j])) << 16));
        sumP[pb + g] = lo | (hi << 32);
        cntP[pb + g] = (unsigned short)an[j];
    }
}

// ---- merge halves + mean + folded affine ----
__global__ void gun_final2(const unsigned long long* __restrict__ sumP,
                           const unsigned short* __restrict__ cntP,
                           const float* __restrict__ xg, const float* __restrict__ P,
                           float* __restrict__ out) {
    __shared__ float sP[48];
    if (threadIdx.x < 48) sP[threadIdx.x] = P[threadIdx.x];
    __syncthreads();
    int G = blockIdx.x * blockDim.x + threadIdx.x;
    if (G >= N_GUN) return;
    unsigned int b = bucket_of((unsigned)G);
    unsigned int g = (unsigned)G - b * GPB;
    size_t i0 = (size_t)(2 * b) * GPB + g;
    size_t i1 = (size_t)(2 * b + 1) * GPB + g;
    unsigned long long v0 = sumP[i0], v1 = sumP[i1];
    float cnt = (float)cntP[i0] + (float)cntP[i1];
    float m0 = __uint_as_float(((unsigned int)v0 & 0xffffu) << 16)
             + __uint_as_float(((unsigned int)v1 & 0xffffu) << 16);
    float m1 = __uint_as_float((unsigned int)v0 & 0xffff0000u)
             + __uint_as_float((unsigned int)v1 & 0xffff0000u);
    float m2 = __uint_as_float(((unsigned int)(v0 >> 32) & 0xffffu) << 16)
             + __uint_as_float(((unsigned int)(v1 >> 32) & 0xffffu) << 16);
    float m3 = __uint_as_float((unsigned int)(v0 >> 32) & 0xffff0000u)
             + __uint_as_float((unsigned int)(v1 >> 32) & 0xffff0000u);
    float inv = 1.0f / fmaxf(cnt, 1.0f);
    m0 *= inv; m1 *= inv; m2 *= inv; m3 *= inv;
    float xv = xg[G];
    float res[OUTD];
#pragma unroll
    for (int o = 0; o < OUTD; ++o) {
        res[o] = m0 * sP[o] + m1 * sP[8 + o] + m2 * sP[16 + o] + m3 * sP[24 + o]
               + xv * sP[32 + o] + sP[40 + o];
    }
    float4* op = (float4*)(out + (size_t)G * OUTD);
    op[0] = make_float4(res[0], res[1], res[2], res[3]);
    op[1] = make_float4(res[4], res[5], res[6], res[7]);
}

// ---- bucket_v9 (round-17 proven, non-split fallback) ----
__global__ __launch_bounds__(256)
void bucket_v9(const unsigned int* __restrict__ stab,
               const unsigned int* __restrict__ payload,
               const uint2* __restrict__ xeb,
               const float* __restrict__ xg,
               const float* __restrict__ P,
               float* __restrict__ out) {
    __shared__ unsigned long long sorted[CH];
    __shared__ unsigned int cnt[1024];
    __shared__ unsigned int base_[1024];
    __shared__ unsigned int partial[256];
    __shared__ float sP[48];
    int t = threadIdx.x;
    if (t < 48) sP[t] = P[t];
    __syncthreads();
    float a0[4] = {0,0,0,0}, a1[4] = {0,0,0,0}, a2[4] = {0,0,0,0}, a3[4] = {0,0,0,0};
    float an[4] = {0,0,0,0};
    unsigned int b = blockIdx.x;
    unsigned int rot = get_xcc() & (NS - 1u);
    for (int si = 0; si < NS; ++si) {
        unsigned int s = ((unsigned int)si + rot) & (NS - 1u);
        unsigned int rs = stab[b * (NS + 1) + s];
        unsigned int re = stab[b * (NS + 1) + s + 1];
        for (unsigned int cs = rs; cs < re; cs += CH) {
            int n = (int)((re - cs < (unsigned int)CH) ? (re - cs) : (unsigned int)CH);
            for (int i = t; i < 1024; i += 256) cnt[i] = 0;
            __syncthreads();
            unsigned int g_[CEPT], r_[CEPT];
            uint2 q_[CEPT];
#pragma unroll
            for (int k = 0; k < CEPT; ++k) {
                int idx = k * 256 + t;
                if (idx < n) {
                    unsigned int p = payload[cs + idx];
                    q_[k] = xeb[p >> 10];
                    unsigned int g = p & 1023u;
                    g_[k] = g;
                    r_[k] = atomicAdd(&cnt[g], 1u);
                } else g_[k] = 0xFFFFFFFFu;
            }
            __syncthreads();
            unsigned int myc[4];
            unsigned int loc[4];
            unsigned int acc = 0;
#pragma unroll
            for (int j = 0; j < 4; ++j) {
                myc[j] = cnt[t * 4 + j];
                loc[j] = acc; acc += myc[j];
            }
            partial[t] = acc;
            __syncthreads();
            for (int d = 1; d < 256; d <<= 1) {
                unsigned int v = (t >= d) ? partial[t - d] : 0u;
                __syncthreads();
                partial[t] += v;
                __syncthreads();
            }
            unsigned int excl = (t > 0) ? partial[t - 1] : 0u;
            unsigned int myb[4];
#pragma unroll
            for (int j = 0; j < 4; ++j) {
                myb[j] = excl + loc[j];
                base_[t * 4 + j] = myb[j];
            }
            __syncthreads();
#pragma unroll
            for (int k = 0; k < CEPT; ++k) {
                if (g_[k] != 0xFFFFFFFFu) {
                    sorted[base_[g_[k]] + r_[k]] =
                        ((unsigned long long)q_[k].y << 32) | (unsigned long long)q_[k].x;
                }
            }
            __syncthreads();
#pragma unroll
            for (int j = 0; j < 4; ++j) {
                unsigned int bs = myb[j], c = myc[j];
                for (unsigned int p2 = bs; p2 < bs + c; ++p2) {
                    unsigned long long v = sorted[p2];
                    unsigned int lo = (unsigned int)v, hi = (unsigned int)(v >> 32);
                    a0[j] += __uint_as_float(lo << 16);
                    a1[j] += __uint_as_float(lo & 0xffff0000u);
                    a2[j] += __uint_as_float(hi << 16);
                    a3[j] += __uint_as_float(hi & 0xffff0000u);
                }
                an[j] += (float)c;
            }
            __syncthreads();
        }
    }
#pragma unroll
    for (int j = 0; j < 4; ++j) {
        int g = t * 4 + j;
        if (g >= GPB) continue;
        unsigned int G = b * GPB + (unsigned int)g;
        if (G >= N_GUN) continue;
        float inv = 1.0f / fmaxf(an[j], 1.0f);
        float m0 = a0[j] * inv, m1 = a1[j] * inv, m2 = a2[j] * inv, m3 = a3[j] * inv;
        float xv = xg[G];
        float res[OUTD];
#pragma unroll
        for (int o = 0; o < OUTD; ++o) {
            res[o] = m0 * sP[o] + m1 * sP[8 + o] + m2 * sP[16 + o] + m3 * sP[24 + o]
                   + xv * sP[32 + o] + sP[40 + o];
        }
        float4* op = (float4*)(out + (size_t)G * OUTD);
        op[0] = make_float4(res[0], res[1], res[2], res[3]);
        op[1] = make_float4(res[4], res[5], res[6], res[7]);
    }
}

// ================= atomic fallback (tiny ws) =================================
__global__ void edge_kernel(const int4* __restrict__ esrc4, const int4* __restrict__ edst4,
                            const float4* __restrict__ xe, float* __restrict__ summed,
                            float* __restrict__ counts) {
    int t = blockIdx.x * blockDim.x + threadIdx.x;
    if (t >= N_EDGES / 4) return;
    int4 s4 = esrc4[t];
    int4 d4 = edst4[t];
    int ss[4] = { s4.x, s4.y, s4.z, s4.w };
    int dd[4] = { d4.x, d4.y, d4.z, d4.w };
#pragma unroll
    for (int k = 0; k < 4; ++k) {
        float4 m = xe[ss[k]];
        float* basep = summed + (size_t)dd[k] * 4;
        atomicAdd(basep + 0, m.x);
        atomicAdd(basep + 1, m.y);
        atomicAdd(basep + 2, m.z);
        atomicAdd(basep + 3, m.w);
        atomicAdd(counts + dd[k], 1.0f);
    }
}

__global__ void gun_kernel(const float4* __restrict__ summed, const float* __restrict__ counts,
                           const float* __restrict__ xg, const float* __restrict__ P,
                           float* __restrict__ out) {
    __shared__ float sP[48];
    if (threadIdx.x < 48) sP[threadIdx.x] = P[threadIdx.x];
    __syncthreads();
    int g = blockIdx.x * blockDim.x + threadIdx.x;
    if (g >= N_GUN) return;
    float4 s = summed[g];
    float cnt = counts[g];
    float inv = 1.0f / fmaxf(cnt, 1.0f);
    float m0 = s.x * inv, m1 = s.y * inv, m2 = s.z * inv, m3 = s.w * inv;
    float xv = xg[g];
    float res[OUTD];
#pragma unroll
    for (int o = 0; o < OUTD; ++o) {
        res[o] = m0 * sP[o] + m1 * sP[8 + o] + m2 * sP[16 + o] + m3 * sP[24 + o]
               + xv * sP[32 + o] + sP[40 + o];
    }
    float4* op = (float4*)(out + (size_t)g * OUTD);
    op[0] = make_float4(res[0], res[1], res[2], res[3]);
    op[1] = make_float4(res[4], res[5], res[6], res[7]);
}

extern "C" void kernel_launch(void* const* d_in, const int* in_sizes, int n_in,
                              void* d_out, int out_size, void* d_ws, size_t ws_size,
                              hipStream_t stream) {
    const float* x_enemy = (const float*)d_in[0];
    const float* x_gun   = (const float*)d_in[1];
    const int*   esrc    = (const int*)d_in[2];
    const int*   edst    = (const int*)d_in[3];
    const float* W_l     = (const float*)d_in[4];
    const float* b_l     = (const float*)d_in[5];
    const float* W_r     = (const float*)d_in[6];
    const float* W_fc    = (const float*)d_in[7];
    const float* b_fc    = (const float*)d_in[8];
    float* out = (float*)d_out;

    // ws layout (u32 units). tileh (u16, [3907][1024]=8MB) aliases xeb region.
    const size_t PAYLOAD_OFF = 0;                            // 16M u32 = 64 MB
    const size_t XEB_OFF     = (size_t)N_EDGES;              // 8M u32 = 32 MB
    const size_t TOT_OFF     = XEB_OFF + (size_t)N_ENEMY*2;  // +1024
    const size_t OFFS_OFF    = TOT_OFF + NB;                 // +1025
    const size_t P_OFF       = OFFS_OFF + NB + 1;            // +48
    const size_t STAB_OFF    = P_OFF + 48;                   // +NB*(NS+1)
    const size_t END17       = STAB_OFF + (size_t)NB * (NS + 1) + 16;
    const size_t SUMP_OFF    = (END17 + 1) & ~(size_t)1;     // u64-aligned
    const size_t CNTP_OFF    = SUMP_OFF + (size_t)2 * NB * GPB * 2;  // u64[2*NB*GPB]
    const size_t END_SPLIT   = CNTP_OFF + ((size_t)2 * NB * GPB + 1) / 2;
    const size_t NEEDED_17   = END17 * sizeof(unsigned int);
    const size_t NEEDED_SPL  = END_SPLIT * sizeof(unsigned int);

    if (ws_size >= NEEDED_17) {
        unsigned int*   ws      = (unsigned int*)d_ws;
        unsigned int*   payload = ws + PAYLOAD_OFF;
        uint2*          xeb     = (uint2*)(ws + XEB_OFF);
        unsigned short* tileh   = (unsigned short*)(ws + XEB_OFF);  // alias, dead before conv
        unsigned int*   tot     = ws + TOT_OFF;
        unsigned int*   offsets = ws + OFFS_OFF;
        float*          P       = (float*)(ws + P_OFF);
        unsigned int*   stab    = ws + STAB_OFF;

        prep_params<<<1, 64, 0, stream>>>(W_l, b_l, W_r, W_fc, b_fc, P);
        hist2_kernel<<<NT4, 256, 0, stream>>>(edst, tileh);
        tile_scanT<16><<<NB / 16, 256, 0, stream>>>(tileh, tot, NB, NT4);
        scan_kernel<<<1, 1024, 0, stream>>>(tot, offsets);
        scatter_sorted<<<NT4, 256, 0, stream>>>(esrc, edst, offsets, tileh, payload);
        slice_sort<<<NB, 256, 0, stream>>>(offsets, payload, stab);
        conv_kernel<<<(N_ENEMY + 255) / 256, 256, 0, stream>>>((const uint4*)x_enemy, xeb);

        if (ws_size >= NEEDED_SPL) {
            unsigned long long* sumP = (unsigned long long*)(ws + SUMP_OFF);
            unsigned short*     cntP = (unsigned short*)(ws + CNTP_OFF);
            bucket_v9s<<<NB * 2, 256, 0, stream>>>(stab, payload, xeb, sumP, cntP);
            gun_final2<<<(N_GUN + 255) / 256, 256, 0, stream>>>(sumP, cntP, x_gun, P, out);
        } else {
            bucket_v9<<<NB, 256, 0, stream>>>(stab, payload, xeb, x_gun, P, out);
        }
    } else {
        float* summed = (float*)d_ws;
        float* counts = summed + (size_t)N_GUN * 4;
        float* P      = counts + N_GUN;
        hipMemsetAsync(d_ws, 0, ((size_t)N_GUN * 5 + 48) * sizeof(float), stream);
        prep_params<<<1, 64, 0, stream>>>(W_l, b_l, W_r, W_fc, b_fc, P);
        int edge_threads = N_EDGES / 4;
        edge_kernel<<<(edge_threads + 255) / 256, 256, 0, stream>>>(
            (const int4*)esrc, (const int4*)edst, (const float4*)x_enemy, summed, counts);
        gun_kernel<<<(N_GUN + 255) / 256, 256, 0, stream>>>(
            (const float4*)summed, counts, x_gun, P, out);
    }
}

// Round 21
// 415.294 us; speedup vs baseline: 1.2393x; 1.1120x over previous
//
#include <hip/hip_runtime.h>

#define N_ENEMY 4000000
#define N_GUN   1000000
#define N_EDGES 16000000
#define OUTD    8

#define NB   1024      // dst buckets
#define GPB  977       // guns per bucket
#define T4   4096      // scatter tile
#define NT4  3907      // ceil(16M/4096)
#define EPT4 16

#define CH   1024      // non-split bucket chunk
#define CEPT 4
#define CHS  512       // split bucket chunk (one per half per ~977-edge run)
#define CEPTS 2

#define NS   16        // src slices: 256K enemies = 2MB bf16 = half XCD L2
#define SEG_CAP 16128  // slice_sort LDS capacity

// exact floor(dst/977) for dst <= 1M
__device__ __forceinline__ unsigned int bucket_of(unsigned int dst) {
    return (unsigned int)(((unsigned long long)dst * 1125395730ull) >> 40);
}
__device__ __forceinline__ unsigned int rne_bf16(unsigned int u) {
    return (u + 0x7FFFu + ((u >> 16) & 1u)) >> 16;
}
__device__ __forceinline__ unsigned int get_xcc() {
    unsigned int x;
    asm("s_getreg_b32 %0, hwreg(HW_REG_XCC_ID)" : "=s"(x));
    return x;
}

// ---- Fold W_l@W_fc (4x8), W_r@W_fc (8), b_l@W_fc + b_fc (8) into P[48] ----
__global__ void prep_params(const float* __restrict__ W_l, const float* __restrict__ b_l,
                            const float* __restrict__ W_r, const float* __restrict__ W_fc,
                            const float* __restrict__ b_fc, float* __restrict__ P) {
    int o = threadIdx.x;
    if (o < OUTD) {
        float a0 = 0.f, a1 = 0.f, a2 = 0.f, a3 = 0.f, r = 0.f, c = 0.f;
        for (int h = 0; h < 64; ++h) {
            float w = W_fc[h * OUTD + o];
            a0 += W_l[0 * 64 + h] * w;
            a1 += W_l[1 * 64 + h] * w;
            a2 += W_l[2 * 64 + h] * w;
            a3 += W_l[3 * 64 + h] * w;
            r  += W_r[h] * w;
            c  += b_l[h] * w;
        }
        P[0 * OUTD + o] = a0;
        P[1 * OUTD + o] = a1;
        P[2 * OUTD + o] = a2;
        P[3 * OUTD + o] = a3;
        P[4 * OUTD + o] = r;
        P[5 * OUTD + o] = c + b_fc[o];
    }
}

// ---- Convert x_enemy f32x4 -> bf16x4 (packed into uint2) ----
__global__ void conv_kernel(const uint4* __restrict__ xe, uint2* __restrict__ xeb) {
    int i = blockIdx.x * blockDim.x + threadIdx.x;
    if (i >= N_ENEMY) return;
    uint4 v = xe[i];
    uint2 q;
    q.x = rne_bf16(v.x) | (rne_bf16(v.y) << 16);
    q.y = rne_bf16(v.z) | (rne_bf16(v.w) << 16);
    xeb[i] = q;
}

// ---- per-tile dst-bucket histogram (T=4096) ----
__global__ void hist2_kernel(const int* __restrict__ edst, unsigned short* __restrict__ tileh) {
    __shared__ unsigned int lh[NB];
    int t = threadIdx.x;
    for (int i = t; i < NB; i += 256) lh[i] = 0;
    __syncthreads();
    int ebase = blockIdx.x * T4;
    int nE = N_EDGES - ebase;
    if (nE > T4) nE = T4;
    for (int i = t; i < nE; i += 256)
        atomicAdd(&lh[bucket_of((unsigned)edst[ebase + i])], 1u);
    __syncthreads();
    unsigned short* row = tileh + (size_t)blockIdx.x * NB;
    for (int i = t; i < NB; i += 256) row[i] = (unsigned short)lh[i];
}

// ---- per-bucket exclusive prefix over tiles (in-place) + totals ----
template<int K>
__global__ __launch_bounds__(256)
void tile_scanT(unsigned short* __restrict__ tileh, unsigned int* __restrict__ tot,
                int nbk, int ntile) {
    __shared__ unsigned int part[256][17];
    int t = threadIdx.x;
    int b0 = blockIdx.x * 16;
    unsigned int loc[16];
#pragma unroll
    for (int j = 0; j < 16; ++j) loc[j] = 0;
    for (int k = 0; k < K; ++k) {
        int tile = t * K + k;
        if (tile < ntile) {
            const unsigned short* row = tileh + (size_t)tile * nbk + b0;
#pragma unroll
            for (int j = 0; j < 16; ++j) loc[j] += row[j];
        }
    }
#pragma unroll
    for (int j = 0; j < 16; ++j) part[t][j] = loc[j];
    __syncthreads();
    if (t < 16) {
        unsigned int acc = 0;
        for (int i = 0; i < 256; ++i) {
            unsigned int v = part[i][t];
            part[i][t] = acc;
            acc += v;
        }
        tot[b0 + t] = acc;
    }
    __syncthreads();
    unsigned int run[16];
#pragma unroll
    for (int j = 0; j < 16; ++j) run[j] = part[t][j];
    for (int k = 0; k < K; ++k) {
        int tile = t * K + k;
        if (tile < ntile) {
            unsigned short* row = tileh + (size_t)tile * nbk + b0;
#pragma unroll
            for (int j = 0; j < 16; ++j) {
                unsigned int c = row[j];
                row[j] = (unsigned short)run[j];
                run[j] += c;
            }
        }
    }
}

__global__ void scan_kernel(const unsigned int* __restrict__ tot,
                            unsigned int* __restrict__ offsets) {
    __shared__ unsigned int tmp[1024];
    int t = threadIdx.x;
    unsigned int v0 = (t < NB) ? tot[t] : 0u;
    tmp[t] = v0;
    __syncthreads();
    for (int d = 1; d < 1024; d <<= 1) {
        unsigned int v = (t >= d) ? tmp[t - d] : 0u;
        __syncthreads();
        tmp[t] += v;
        __syncthreads();
    }
    if (t < NB) offsets[t] = tmp[t] - v0;
    if (t == NB - 1) offsets[NB] = tmp[t];
}

// ---- tile-sorted partition by dst bucket (T=4096, 4 blocks/CU) ----
__global__ __launch_bounds__(256, 4)
void scatter_sorted(const int* __restrict__ esrc, const int* __restrict__ edst,
                    const unsigned int* __restrict__ offsets,
                    const unsigned short* __restrict__ tileh,
                    unsigned int* __restrict__ payload) {
    __shared__ unsigned int cnt[NB];
    __shared__ unsigned int base[NB];
    __shared__ unsigned int gb[NB];
    __shared__ unsigned short bOf[T4];
    __shared__ unsigned int sorted[T4];
    __shared__ unsigned int partial[256];
    int t = threadIdx.x;
    int tile = blockIdx.x;
    int ebase = tile * T4;
    int nE = N_EDGES - ebase;
    if (nE > T4) nE = T4;
    for (int i = t; i < NB; i += 256) cnt[i] = 0;
    __syncthreads();
    unsigned int w[EPT4];
    unsigned int br[EPT4];
#pragma unroll
    for (int k = 0; k < EPT4; ++k) {
        int idx = k * 256 + t;
        if (idx < nE) {
            unsigned int s = (unsigned int)esrc[ebase + idx];
            unsigned int d = (unsigned int)edst[ebase + idx];
            unsigned int b = bucket_of(d);
            unsigned int g = d - b * GPB;
            unsigned int r = atomicAdd(&cnt[b], 1u);
            w[k]  = (s << 10) | g;
            br[k] = (b << 13) | r;
        } else br[k] = 0xFFFFFFFFu;
    }
    __syncthreads();
    unsigned int loc[4];
    unsigned int s = 0;
#pragma unroll
    for (int j = 0; j < 4; ++j) {
        int b = t * 4 + j;
        unsigned int c = cnt[b];
        loc[j] = s; s += c;
    }
    partial[t] = s;
    __syncthreads();
    for (int d = 1; d < 256; d <<= 1) {
        unsigned int v = (t >= d) ? partial[t - d] : 0u;
        __syncthreads();
        partial[t] += v;
        __syncthreads();
    }
    unsigned int excl = (t > 0) ? partial[t - 1] : 0u;
#pragma unroll
    for (int j = 0; j < 4; ++j) base[t * 4 + j] = excl + loc[j];
    __syncthreads();
    const unsigned short* trow = tileh + (size_t)tile * NB;
#pragma unroll
    for (int j = 0; j < 4; ++j) {
        int b = t * 4 + j;
        gb[b] = offsets[b] + (unsigned int)trow[b];
        unsigned int bs = base[b];
        unsigned int c = cnt[b];
        for (unsigned int p = bs; p < bs + c; ++p) bOf[p] = (unsigned short)b;
    }
    __syncthreads();
#pragma unroll
    for (int k = 0; k < EPT4; ++k) {
        if (br[k] != 0xFFFFFFFFu) {
            unsigned int b = br[k] >> 13;
            unsigned int r = br[k] & 8191u;
            sorted[base[b] + r] = w[k];
        }
    }
    __syncthreads();
    for (int p = t; p < nE; p += 256) {
        unsigned int b = bOf[p];
        payload[gb[b] + ((unsigned int)p - base[b])] = sorted[p];
    }
}

// ---- per-bucket counting sort by src-slice (slice = w>>28, 16 bins) ----
__global__ __launch_bounds__(256)
void slice_sort(const unsigned int* __restrict__ offsets,
                unsigned int* __restrict__ payload,
                unsigned int* __restrict__ stab) {
    __shared__ unsigned int A[SEG_CAP];
    __shared__ unsigned int cnt[NS];
    __shared__ unsigned int base[NS + 1];
    int b = blockIdx.x;
    int t = threadIdx.x;
    unsigned int segS = offsets[b];
    unsigned int segE = offsets[b + 1];
    unsigned int len = segE - segS;
    if (len > SEG_CAP) {
        if (t <= NS) stab[b * (NS + 1) + t] = (t == 0) ? segS : segE;
        return;
    }
    if (t < NS) cnt[t] = 0;
    __syncthreads();
    for (unsigned int i = t; i < len; i += 256) {
        unsigned int w = payload[segS + i];
        A[i] = w;
        atomicAdd(&cnt[w >> 28], 1u);
    }
    __syncthreads();
    if (t == 0) {
        unsigned int acc = 0;
        for (int k = 0; k < NS; ++k) { base[k] = acc; acc += cnt[k]; }
        base[NS] = acc;
    }
    __syncthreads();
    if (t < NS) cnt[t] = 0;
    __syncthreads();
    for (unsigned int i = t; i < len; i += 256) {
        unsigned int w = A[i];
        unsigned int k = w >> 28;
        unsigned int r = atomicAdd(&cnt[k], 1u);
        payload[segS + base[k] + r] = w;
    }
    if (t <= NS) stab[b * (NS + 1) + t] = segS + base[t];
}

// ---- bucket_v9s: CHUNK-PARITY split (2 blocks/bucket), CHS=512, NS=16 ----
__global__ __launch_bounds__(256)
void bucket_v9s(const unsigned int* __restrict__ stab,
                const unsigned int* __restrict__ payload,
                const uint2* __restrict__ xeb,
                unsigned long long* __restrict__ sumP,
                unsigned short* __restrict__ cntP) {
    __shared__ unsigned long long sorted[CHS];  // 4 KB
    __shared__ unsigned int cnt[1024];
    __shared__ unsigned int base_[1024];
    __shared__ unsigned int partial[256];
    int t = threadIdx.x;

    float a0[4] = {0,0,0,0}, a1[4] = {0,0,0,0}, a2[4] = {0,0,0,0}, a3[4] = {0,0,0,0};
    float an[4] = {0,0,0,0};

    unsigned int b    = (unsigned int)blockIdx.x >> 1;
    unsigned int half = (unsigned int)blockIdx.x & 1u;
    unsigned int rot = (get_xcc() & 7u) << 1;   // order-only; partition is rot-independent

    for (int si = 0; si < NS; ++si) {
        unsigned int s = ((unsigned int)si + rot) & (NS - 1u);
        unsigned int rs = stab[b * (NS + 1) + s];
        unsigned int re = stab[b * (NS + 1) + s + 1];

        // chunk-parity split: half h takes chunks h, h+2, ... of this slice-run
        for (unsigned int cs = rs + half * CHS; cs < re; cs += 2u * CHS) {
            int n = (int)((re - cs < (unsigned int)CHS) ? (re - cs) : (unsigned int)CHS);
            for (int i = t; i < 1024; i += 256) cnt[i] = 0;
            __syncthreads();

            unsigned int g_[CEPTS], r_[CEPTS];
            uint2 q_[CEPTS];
#pragma unroll
            for (int k = 0; k < CEPTS; ++k) {
                int idx = k * 256 + t;
                if (idx < n) {
                    unsigned int p = payload[cs + idx];
                    q_[k] = xeb[p >> 10];
                    unsigned int g = p & 1023u;
                    g_[k] = g;
                    r_[k] = atomicAdd(&cnt[g], 1u);   // ONE atomic: rank AND hist
                } else g_[k] = 0xFFFFFFFFu;
            }
            __syncthreads();

            unsigned int myc[4];
            unsigned int loc[4];
            unsigned int acc = 0;
#pragma unroll
            for (int j = 0; j < 4; ++j) {
                myc[j] = cnt[t * 4 + j];
                loc[j] = acc; acc += myc[j];
            }
            partial[t] = acc;
            __syncthreads();
            for (int d = 1; d < 256; d <<= 1) {
                unsigned int v = (t >= d) ? partial[t - d] : 0u;
                __syncthreads();
                partial[t] += v;
                __syncthreads();
            }
            unsigned int excl = (t > 0) ? partial[t - 1] : 0u;
            unsigned int myb[4];
#pragma unroll
            for (int j = 0; j < 4; ++j) {
                myb[j] = excl + loc[j];
                base_[t * 4 + j] = myb[j];
            }
            __syncthreads();

#pragma unroll
            for (int k = 0; k < CEPTS; ++k) {
                if (g_[k] != 0xFFFFFFFFu) {
                    sorted[base_[g_[k]] + r_[k]] =
                        ((unsigned long long)q_[k].y << 32) | (unsigned long long)q_[k].x;
                }
            }
            __syncthreads();

#pragma unroll
            for (int j = 0; j < 4; ++j) {
                unsigned int bs = myb[j], c = myc[j];
                for (unsigned int p2 = bs; p2 < bs + c; ++p2) {
                    unsigned long long v = sorted[p2];
                    unsigned int lo = (unsigned int)v, hi = (unsigned int)(v >> 32);
                    a0[j] += __uint_as_float(lo << 16);
                    a1[j] += __uint_as_float(lo & 0xffff0000u);
                    a2[j] += __uint_as_float(hi << 16);
                    a3[j] += __uint_as_float(hi & 0xffff0000u);
                }
                an[j] += (float)c;
            }
            __syncthreads();
        }
    }

    // write bf16x4-packed partial + u16 count (round-20-proven format)
    size_t pb = (size_t)blockIdx.x * GPB;
#pragma unroll
    for (int j = 0; j < 4; ++j) {
        int g = t * 4 + j;
        if (g >= GPB) continue;
        unsigned long long lo = (unsigned long long)(rne_bf16(__float_as_uint(a0[j])) |
                                                    (rne_bf16(__float_as_uint(a1[j])) << 16));
        unsigned long long hi = (unsigned long long)(rne_bf16(__float_as_uint(a2[j])) |
                                                    (rne_bf16(__float_as_uint(a3[j])) << 16));
        sumP[pb + g] = lo | (hi << 32);
        cntP[pb + g] = (unsigned short)an[j];
    }
}

// ---- merge halves + mean + folded affine ----
__global__ void gun_final2(const unsigned long long* __restrict__ sumP,
                           const unsigned short* __restrict__ cntP,
                           const float* __restrict__ xg, const float* __restrict__ P,
                           float* __restrict__ out) {
    __shared__ float sP[48];
    if (threadIdx.x < 48) sP[threadIdx.x] = P[threadIdx.x];
    __syncthreads();
    int G = blockIdx.x * blockDim.x + threadIdx.x;
    if (G >= N_GUN) return;
    unsigned int b = bucket_of((unsigned)G);
    unsigned int g = (unsigned)G - b * GPB;
    size_t i0 = (size_t)(2 * b) * GPB + g;
    size_t i1 = (size_t)(2 * b + 1) * GPB + g;
    unsigned long long v0 = sumP[i0], v1 = sumP[i1];
    float cnt = (float)cntP[i0] + (float)cntP[i1];
    float m0 = __uint_as_float(((unsigned int)v0 & 0xffffu) << 16)
             + __uint_as_float(((unsigned int)v1 & 0xffffu) << 16);
    float m1 = __uint_as_float((unsigned int)v0 & 0xffff0000u)
             + __uint_as_float((unsigned int)v1 & 0xffff0000u);
    float m2 = __uint_as_float(((unsigned int)(v0 >> 32) & 0xffffu) << 16)
             + __uint_as_float(((unsigned int)(v1 >> 32) & 0xffffu) << 16);
    float m3 = __uint_as_float((unsigned int)(v0 >> 32) & 0xffff0000u)
             + __uint_as_float((unsigned int)(v1 >> 32) & 0xffff0000u);
    float inv = 1.0f / fmaxf(cnt, 1.0f);
    m0 *= inv; m1 *= inv; m2 *= inv; m3 *= inv;
    float xv = xg[G];
    float res[OUTD];
#pragma unroll
    for (int o = 0; o < OUTD; ++o) {
        res[o] = m0 * sP[o] + m1 * sP[8 + o] + m2 * sP[16 + o] + m3 * sP[24 + o]
               + xv * sP[32 + o] + sP[40 + o];
    }
    float4* op = (float4*)(out + (size_t)G * OUTD);
    op[0] = make_float4(res[0], res[1], res[2], res[3]);
    op[1] = make_float4(res[4], res[5], res[6], res[7]);
}

// ---- bucket_v9 (non-split fallback, NS=16) ----
__global__ __launch_bounds__(256)
void bucket_v9(const unsigned int* __restrict__ stab,
               const unsigned int* __restrict__ payload,
               const uint2* __restrict__ xeb,
               const float* __restrict__ xg,
               const float* __restrict__ P,
               float* __restrict__ out) {
    __shared__ unsigned long long sorted[CH];
    __shared__ unsigned int cnt[1024];
    __shared__ unsigned int base_[1024];
    __shared__ unsigned int partial[256];
    __shared__ float sP[48];
    int t = threadIdx.x;
    if (t < 48) sP[t] = P[t];
    __syncthreads();
    float a0[4] = {0,0,0,0}, a1[4] = {0,0,0,0}, a2[4] = {0,0,0,0}, a3[4] = {0,0,0,0};
    float an[4] = {0,0,0,0};
    unsigned int b = blockIdx.x;
    unsigned int rot = (get_xcc() & 7u) << 1;
    for (int si = 0; si < NS; ++si) {
        unsigned int s = ((unsigned int)si + rot) & (NS - 1u);
        unsigned int rs = stab[b * (NS + 1) + s];
        unsigned int re = stab[b * (NS + 1) + s + 1];
        for (unsigned int cs = rs; cs < re; cs += CH) {
            int n = (int)((re - cs < (unsigned int)CH) ? (re - cs) : (unsigned int)CH);
            for (int i = t; i < 1024; i += 256) cnt[i] = 0;
            __syncthreads();
            unsigned int g_[CEPT], r_[CEPT];
            uint2 q_[CEPT];
#pragma unroll
            for (int k = 0; k < CEPT; ++k) {
                int idx = k * 256 + t;
                if (idx < n) {
                    unsigned int p = payload[cs + idx];
                    q_[k] = xeb[p >> 10];
                    unsigned int g = p & 1023u;
                    g_[k] = g;
                    r_[k] = atomicAdd(&cnt[g], 1u);
                } else g_[k] = 0xFFFFFFFFu;
            }
            __syncthreads();
            unsigned int myc[4];
            unsigned int loc[4];
            unsigned int acc = 0;
#pragma unroll
            for (int j = 0; j < 4; ++j) {
                myc[j] = cnt[t * 4 + j];
                loc[j] = acc; acc += myc[j];
            }
            partial[t] = acc;
            __syncthreads();
            for (int d = 1; d < 256; d <<= 1) {
                unsigned int v = (t >= d) ? partial[t - d] : 0u;
                __syncthreads();
                partial[t] += v;
                __syncthreads();
            }
            unsigned int excl = (t > 0) ? partial[t - 1] : 0u;
            unsigned int myb[4];
#pragma unroll
            for (int j = 0; j < 4; ++j) {
                myb[j] = excl + loc[j];
                base_[t * 4 + j] = myb[j];
            }
            __syncthreads();
#pragma unroll
            for (int k = 0; k < CEPT; ++k) {
                if (g_[k] != 0xFFFFFFFFu) {
                    sorted[base_[g_[k]] + r_[k]] =
                        ((unsigned long long)q_[k].y << 32) | (unsigned long long)q_[k].x;
                }
            }
            __syncthreads();
#pragma unroll
            for (int j = 0; j < 4; ++j) {
                unsigned int bs = myb[j], c = myc[j];
                for (unsigned int p2 = bs; p2 < bs + c; ++p2) {
                    unsigned long long v = sorted[p2];
                    unsigned int lo = (unsigned int)v, hi = (unsigned int)(v >> 32);
                    a0[j] += __uint_as_float(lo << 16);
                    a1[j] += __uint_as_float(lo & 0xffff0000u);
                    a2[j] += __uint_as_float(hi << 16);
                    a3[j] += __uint_as_float(hi & 0xffff0000u);
                }
                an[j] += (float)c;
            }
            __syncthreads();
        }
    }
#pragma unroll
    for (int j = 0; j < 4; ++j) {
        int g = t * 4 + j;
        if (g >= GPB) continue;
        unsigned int G = b * GPB + (unsigned int)g;
        if (G >= N_GUN) continue;
        float inv = 1.0f / fmaxf(an[j], 1.0f);
        float m0 = a0[j] * inv, m1 = a1[j] * inv, m2 = a2[j] * inv, m3 = a3[j] * inv;
        float xv = xg[G];
        float res[OUTD];
#pragma unroll
        for (int o = 0; o < OUTD; ++o) {
            res[o] = m0 * sP[o] + m1 * sP[8 + o] + m2 * sP[16 + o] + m3 * sP[24 + o]
                   + xv * sP[32 + o] + sP[40 + o];
        }
        float4* op = (float4*)(out + (size_t)G * OUTD);
        op[0] = make_float4(res[0], res[1], res[2], res[3]);
        op[1] = make_float4(res[4], res[5], res[6], res[7]);
    }
}

// ================= atomic fallback (tiny ws) =================================
__global__ void edge_kernel(const int4* __restrict__ esrc4, const int4* __restrict__ edst4,
                            const float4* __restrict__ xe, float* __restrict__ summed,
                            float* __restrict__ counts) {
    int t = blockIdx.x * blockDim.x + threadIdx.x;
    if (t >= N_EDGES / 4) return;
    int4 s4 = esrc4[t];
    int4 d4 = edst4[t];
    int ss[4] = { s4.x, s4.y, s4.z, s4.w };
    int dd[4] = { d4.x, d4.y, d4.z, d4.w };
#pragma unroll
    for (int k = 0; k < 4; ++k) {
        float4 m = xe[ss[k]];
        float* basep = summed + (size_t)dd[k] * 4;
        atomicAdd(basep + 0, m.x);
        atomicAdd(basep + 1, m.y);
        atomicAdd(basep + 2, m.z);
        atomicAdd(basep + 3, m.w);
        atomicAdd(counts + dd[k], 1.0f);
    }
}

__global__ void gun_kernel(const float4* __restrict__ summed, const float* __restrict__ counts,
                           const float* __restrict__ xg, const float* __restrict__ P,
                           float* __restrict__ out) {
    __shared__ float sP[48];
    if (threadIdx.x < 48) sP[threadIdx.x] = P[threadIdx.x];
    __syncthreads();
    int g = blockIdx.x * blockDim.x + threadIdx.x;
    if (g >= N_GUN) return;
    float4 s = summed[g];
    float cnt = counts[g];
    float inv = 1.0f / fmaxf(cnt, 1.0f);
    float m0 = s.x * inv, m1 = s.y * inv, m2 = s.z * inv, m3 = s.w * inv;
    float xv = xg[g];
    float res[OUTD];
#pragma unroll
    for (int o = 0; o < OUTD; ++o) {
        res[o] = m0 * sP[o] + m1 * sP[8 + o] + m2 * sP[16 + o] + m3 * sP[24 + o]
               + xv * sP[32 + o] + sP[40 + o];
    }
    float4* op = (float4*)(out + (size_t)g * OUTD);
    op[0] = make_float4(res[0], res[1], res[2], res[3]);
    op[1] = make_float4(res[4], res[5], res[6], res[7]);
}

extern "C" void kernel_launch(void* const* d_in, const int* in_sizes, int n_in,
                              void* d_out, int out_size, void* d_ws, size_t ws_size,
                              hipStream_t stream) {
    const float* x_enemy = (const float*)d_in[0];
    const float* x_gun   = (const float*)d_in[1];
    const int*   esrc    = (const int*)d_in[2];
    const int*   edst    = (const int*)d_in[3];
    const float* W_l     = (const float*)d_in[4];
    const float* b_l     = (const float*)d_in[5];
    const float* W_r     = (const float*)d_in[6];
    const float* W_fc    = (const float*)d_in[7];
    const float* b_fc    = (const float*)d_in[8];
    float* out = (float*)d_out;

    // ws layout (u32 units). tileh (u16, [3907][1024]=8MB) aliases xeb region.
    const size_t PAYLOAD_OFF = 0;                            // 16M u32 = 64 MB
    const size_t XEB_OFF     = (size_t)N_EDGES;              // 8M u32 = 32 MB
    const size_t TOT_OFF     = XEB_OFF + (size_t)N_ENEMY*2;  // +1024
    const size_t OFFS_OFF    = TOT_OFF + NB;                 // +1025
    const size_t P_OFF       = OFFS_OFF + NB + 1;            // +48
    const size_t STAB_OFF    = P_OFF + 48;                   // +NB*(NS+1)
    const size_t END17       = STAB_OFF + (size_t)NB * (NS + 1) + 16;
    const size_t SUMP_OFF    = (END17 + 1) & ~(size_t)1;     // u64-aligned
    const size_t CNTP_OFF    = SUMP_OFF + (size_t)2 * NB * GPB * 2;  // u64[2*NB*GPB]
    const size_t END_SPLIT   = CNTP_OFF + ((size_t)2 * NB * GPB + 1) / 2;
    const size_t NEEDED_17   = END17 * sizeof(unsigned int);
    const size_t NEEDED_SPL  = END_SPLIT * sizeof(unsigned int);

    if (ws_size >= NEEDED_17) {
        unsigned int*   ws      = (unsigned int*)d_ws;
        unsigned int*   payload = ws + PAYLOAD_OFF;
        uint2*          xeb     = (uint2*)(ws + XEB_OFF);
        unsigned short* tileh   = (unsigned short*)(ws + XEB_OFF);  // alias, dead before conv
        unsigned int*   tot     = ws + TOT_OFF;
        unsigned int*   offsets = ws + OFFS_OFF;
        float*          P       = (float*)(ws + P_OFF);
        unsigned int*   stab    = ws + STAB_OFF;

        prep_params<<<1, 64, 0, stream>>>(W_l, b_l, W_r, W_fc, b_fc, P);
        hist2_kernel<<<NT4, 256, 0, stream>>>(edst, tileh);
        tile_scanT<16><<<NB / 16, 256, 0, stream>>>(tileh, tot, NB, NT4);
        scan_kernel<<<1, 1024, 0, stream>>>(tot, offsets);
        scatter_sorted<<<NT4, 256, 0, stream>>>(esrc, edst, offsets, tileh, payload);
        slice_sort<<<NB, 256, 0, stream>>>(offsets, payload, stab);
        conv_kernel<<<(N_ENEMY + 255) / 256, 256, 0, stream>>>((const uint4*)x_enemy, xeb);

        if (ws_size >= NEEDED_SPL) {
            unsigned long long* sumP = (unsigned long long*)(ws + SUMP_OFF);
            unsigned short*     cntP = (unsigned short*)(ws + CNTP_OFF);
            bucket_v9s<<<NB * 2, 256, 0, stream>>>(stab, payload, xeb, sumP, cntP);
            gun_final2<<<(N_GUN + 255) / 256, 256, 0, stream>>>(sumP, cntP, x_gun, P, out);
        } else {
            bucket_v9<<<NB, 256, 0, stream>>>(stab, payload, xeb, x_gun, P, out);
        }
    } else {
        float* summed = (float*)d_ws;
        float* counts = summed + (size_t)N_GUN * 4;
        float* P      = counts + N_GUN;
        hipMemsetAsync(d_ws, 0, ((size_t)N_GUN * 5 + 48) * sizeof(float), stream);
        prep_params<<<1, 64, 0, stream>>>(W_l, b_l, W_r, W_fc, b_fc, P);
        int edge_threads = N_EDGES / 4;
        edge_kernel<<<(edge_threads + 255) / 256, 256, 0, stream>>>(
            (const int4*)esrc, (const int4*)edst, (const float4*)x_enemy, summed, counts);
        gun_kernel<<<(N_GUN + 255) / 256, 256, 0, stream>>>(
            (const float4*)summed, counts, x_gun, P, out);
    }
}

// Round 22
// 372.269 us; speedup vs baseline: 1.3826x; 1.1156x over previous
//
#include <hip/hip_runtime.h>

#define N_ENEMY 4000000
#define N_GUN   1000000
#define N_EDGES 16000000
#define OUTD    8

#define NB   1024      // dst buckets
#define GPB  977       // guns per bucket
#define T8   8192      // scatter tile
#define NT8  1954      // ceil(16M/8192)
#define EPT8 32

#define CH   2048      // bucket_v9 chunk (16KB sorted -> 25.8KB LDS -> 6 blocks/CU)
#define CEPT 8         // CH/256

#define NS   8         // src slices: 512K enemies = 4MB bf16 = one XCD L2
#define SEG_CAP 16128  // slice_sort LDS capacity

// exact floor(dst/977) for dst <= 1M
__device__ __forceinline__ unsigned int bucket_of(unsigned int dst) {
    return (unsigned int)(((unsigned long long)dst * 1125395730ull) >> 40);
}
__device__ __forceinline__ unsigned int rne_bf16(unsigned int u) {
    return (u + 0x7FFFu + ((u >> 16) & 1u)) >> 16;
}
__device__ __forceinline__ unsigned int get_xcc() {
    unsigned int x;
    asm("s_getreg_b32 %0, hwreg(HW_REG_XCC_ID)" : "=s"(x));
    return x;
}

// ---- Fold W_l@W_fc (4x8), W_r@W_fc (8), b_l@W_fc + b_fc (8) into P[48] ----
__global__ void prep_params(const float* __restrict__ W_l, const float* __restrict__ b_l,
                            const float* __restrict__ W_r, const float* __restrict__ W_fc,
                            const float* __restrict__ b_fc, float* __restrict__ P) {
    int o = threadIdx.x;
    if (o < OUTD) {
        float a0 = 0.f, a1 = 0.f, a2 = 0.f, a3 = 0.f, r = 0.f, c = 0.f;
        for (int h = 0; h < 64; ++h) {
            float w = W_fc[h * OUTD + o];
            a0 += W_l[0 * 64 + h] * w;
            a1 += W_l[1 * 64 + h] * w;
            a2 += W_l[2 * 64 + h] * w;
            a3 += W_l[3 * 64 + h] * w;
            r  += W_r[h] * w;
            c  += b_l[h] * w;
        }
        P[0 * OUTD + o] = a0;
        P[1 * OUTD + o] = a1;
        P[2 * OUTD + o] = a2;
        P[3 * OUTD + o] = a3;
        P[4 * OUTD + o] = r;
        P[5 * OUTD + o] = c + b_fc[o];
    }
}

// ---- Convert x_enemy f32x4 -> bf16x4 (packed into uint2) ----
__global__ void conv_kernel(const uint4* __restrict__ xe, uint2* __restrict__ xeb) {
    int i = blockIdx.x * blockDim.x + threadIdx.x;
    if (i >= N_ENEMY) return;
    uint4 v = xe[i];
    uint2 q;
    q.x = rne_bf16(v.x) | (rne_bf16(v.y) << 16);
    q.y = rne_bf16(v.z) | (rne_bf16(v.w) << 16);
    xeb[i] = q;
}

// ---- per-tile dst-bucket histogram ----
__global__ void hist2_kernel(const int* __restrict__ edst, unsigned short* __restrict__ tileh) {
    __shared__ unsigned int lh[NB];
    int t = threadIdx.x;
    for (int i = t; i < NB; i += 256) lh[i] = 0;
    __syncthreads();
    int ebase = blockIdx.x * T8;
    int nE = N_EDGES - ebase;
    if (nE > T8) nE = T8;
    for (int i = t; i < nE; i += 256)
        atomicAdd(&lh[bucket_of((unsigned)edst[ebase + i])], 1u);
    __syncthreads();
    unsigned short* row = tileh + (size_t)blockIdx.x * NB;
    for (int i = t; i < NB; i += 256) row[i] = (unsigned short)lh[i];
}

// ---- per-bucket exclusive prefix over tiles (in-place) + totals ----
template<int K>
__global__ __launch_bounds__(256)
void tile_scanT(unsigned short* __restrict__ tileh, unsigned int* __restrict__ tot,
                int nbk, int ntile) {
    __shared__ unsigned int part[256][17];
    int t = threadIdx.x;
    int b0 = blockIdx.x * 16;
    unsigned int loc[16];
#pragma unroll
    for (int j = 0; j < 16; ++j) loc[j] = 0;
    for (int k = 0; k < K; ++k) {
        int tile = t * K + k;
        if (tile < ntile) {
            const unsigned short* row = tileh + (size_t)tile * nbk + b0;
#pragma unroll
            for (int j = 0; j < 16; ++j) loc[j] += row[j];
        }
    }
#pragma unroll
    for (int j = 0; j < 16; ++j) part[t][j] = loc[j];
    __syncthreads();
    if (t < 16) {
        unsigned int acc = 0;
        for (int i = 0; i < 256; ++i) {
            unsigned int v = part[i][t];
            part[i][t] = acc;
            acc += v;
        }
        tot[b0 + t] = acc;
    }
    __syncthreads();
    unsigned int run[16];
#pragma unroll
    for (int j = 0; j < 16; ++j) run[j] = part[t][j];
    for (int k = 0; k < K; ++k) {
        int tile = t * K + k;
        if (tile < ntile) {
            unsigned short* row = tileh + (size_t)tile * nbk + b0;
#pragma unroll
            for (int j = 0; j < 16; ++j) {
                unsigned int c = row[j];
                row[j] = (unsigned short)run[j];
                run[j] += c;
            }
        }
    }
}

__global__ void scan_kernel(const unsigned int* __restrict__ tot,
                            unsigned int* __restrict__ offsets) {
    __shared__ unsigned int tmp[1024];
    int t = threadIdx.x;
    unsigned int v0 = (t < NB) ? tot[t] : 0u;
    tmp[t] = v0;
    __syncthreads();
    for (int d = 1; d < 1024; d <<= 1) {
        unsigned int v = (t >= d) ? tmp[t - d] : 0u;
        __syncthreads();
        tmp[t] += v;
        __syncthreads();
    }
    if (t < NB) offsets[t] = tmp[t] - v0;
    if (t == NB - 1) offsets[NB] = tmp[t];
}

// ---- tile-sorted partition by dst bucket; payload = (src<<10)|g; no global atomics ----
__global__ __launch_bounds__(256, 2)
void scatter_sorted(const int* __restrict__ esrc, const int* __restrict__ edst,
                    const unsigned int* __restrict__ offsets,
                    const unsigned short* __restrict__ tileh,
                    unsigned int* __restrict__ payload) {
    __shared__ unsigned int cnt[NB];
    __shared__ unsigned int base[NB];
    __shared__ unsigned int gb[NB];
    __shared__ unsigned short bOf[T8];
    __shared__ unsigned int sorted[T8];
    __shared__ unsigned int partial[256];
    int t = threadIdx.x;
    int tile = blockIdx.x;
    int ebase = tile * T8;
    int nE = N_EDGES - ebase;
    if (nE > T8) nE = T8;
    for (int i = t; i < NB; i += 256) cnt[i] = 0;
    __syncthreads();
    unsigned int w[EPT8];
    unsigned int br[EPT8];
#pragma unroll
    for (int k = 0; k < EPT8; ++k) {
        int idx = k * 256 + t;
        if (idx < nE) {
            unsigned int s = (unsigned int)esrc[ebase + idx];
            unsigned int d = (unsigned int)edst[ebase + idx];
            unsigned int b = bucket_of(d);
            unsigned int g = d - b * GPB;
            unsigned int r = atomicAdd(&cnt[b], 1u);
            w[k]  = (s << 10) | g;
            br[k] = (b << 13) | r;
        } else br[k] = 0xFFFFFFFFu;
    }
    __syncthreads();
    unsigned int loc[4];
    unsigned int s = 0;
#pragma unroll
    for (int j = 0; j < 4; ++j) {
        int b = t * 4 + j;
        unsigned int c = cnt[b];
        loc[j] = s; s += c;
    }
    partial[t] = s;
    __syncthreads();
    for (int d = 1; d < 256; d <<= 1) {
        unsigned int v = (t >= d) ? partial[t - d] : 0u;
        __syncthreads();
        partial[t] += v;
        __syncthreads();
    }
    unsigned int excl = (t > 0) ? partial[t - 1] : 0u;
#pragma unroll
    for (int j = 0; j < 4; ++j) base[t * 4 + j] = excl + loc[j];
    __syncthreads();
    const unsigned short* trow = tileh + (size_t)tile * NB;
#pragma unroll
    for (int j = 0; j < 4; ++j) {
        int b = t * 4 + j;
        gb[b] = offsets[b] + (unsigned int)trow[b];
        unsigned int bs = base[b];
        unsigned int c = cnt[b];
        for (unsigned int p = bs; p < bs + c; ++p) bOf[p] = (unsigned short)b;
    }
    __syncthreads();
#pragma unroll
    for (int k = 0; k < EPT8; ++k) {
        if (br[k] != 0xFFFFFFFFu) {
            unsigned int b = br[k] >> 13;
            unsigned int r = br[k] & 8191u;
            sorted[base[b] + r] = w[k];
        }
    }
    __syncthreads();
    for (int p = t; p < nE; p += 256) {
        unsigned int b = bOf[p];
        payload[gb[b] + ((unsigned int)p - base[b])] = sorted[p];
    }
}

// ---- per-bucket counting sort by src-slice (slice = w>>29, 8 bins) ----
__global__ __launch_bounds__(256)
void slice_sort(const unsigned int* __restrict__ offsets,
                unsigned int* __restrict__ payload,
                unsigned int* __restrict__ stab) {
    __shared__ unsigned int A[SEG_CAP];
    __shared__ unsigned int cnt[NS];
    __shared__ unsigned int base[NS + 1];
    int b = blockIdx.x;
    int t = threadIdx.x;
    unsigned int segS = offsets[b];
    unsigned int segE = offsets[b + 1];
    unsigned int len = segE - segS;
    if (len > SEG_CAP) {
        if (t <= NS) stab[b * (NS + 1) + t] = (t == 0) ? segS : segE;
        return;
    }
    if (t < NS) cnt[t] = 0;
    __syncthreads();
    for (unsigned int i = t; i < len; i += 256) {
        unsigned int w = payload[segS + i];
        A[i] = w;
        atomicAdd(&cnt[w >> 29], 1u);
    }
    __syncthreads();
    if (t == 0) {
        unsigned int acc = 0;
        for (int k = 0; k < NS; ++k) { base[k] = acc; acc += cnt[k]; }
        base[NS] = acc;
    }
    __syncthreads();
    if (t < NS) cnt[t] = 0;
    __syncthreads();
    for (unsigned int i = t; i < len; i += 256) {
        unsigned int w = A[i];
        unsigned int k = w >> 29;
        unsigned int r = atomicAdd(&cnt[k], 1u);
        payload[segS + base[k] + r] = w;
    }
    if (t <= NS) stab[b * (NS + 1) + t] = segS + base[t];
}

// ---- bucket_v9: slice-rotated walk, 1 LDS atomic/edge, CH=2048 ----
__global__ __launch_bounds__(256)
void bucket_v9(const unsigned int* __restrict__ stab,
               const unsigned int* __restrict__ payload,
               const uint2* __restrict__ xeb,
               const float* __restrict__ xg,
               const float* __restrict__ P,
               float* __restrict__ out) {
    __shared__ unsigned long long sorted[CH];   // 16 KB
    __shared__ unsigned int cnt[1024];
    __shared__ unsigned int base_[1024];
    __shared__ unsigned int partial[256];
    __shared__ float sP[48];
    int t = threadIdx.x;
    if (t < 48) sP[t] = P[t];
    __syncthreads();

    float a0[4] = {0,0,0,0}, a1[4] = {0,0,0,0}, a2[4] = {0,0,0,0}, a3[4] = {0,0,0,0};
    float an[4] = {0,0,0,0};

    unsigned int b = blockIdx.x;
    unsigned int rot = get_xcc() & (NS - 1u);

    for (int si = 0; si < NS; ++si) {
        unsigned int s = ((unsigned int)si + rot) & (NS - 1u);
        unsigned int rs = stab[b * (NS + 1) + s];
        unsigned int re = stab[b * (NS + 1) + s + 1];

        for (unsigned int cs = rs; cs < re; cs += CH) {
            int n = (int)((re - cs < (unsigned int)CH) ? (re - cs) : (unsigned int)CH);
            for (int i = t; i < 1024; i += 256) cnt[i] = 0;
            __syncthreads();

            unsigned int g_[CEPT], r_[CEPT];
            uint2 q_[CEPT];
#pragma unroll
            for (int k = 0; k < CEPT; ++k) {
                int idx = k * 256 + t;
                if (idx < n) {
                    unsigned int p = payload[cs + idx];
                    q_[k] = xeb[p >> 10];
                    unsigned int g = p & 1023u;
                    g_[k] = g;
                    r_[k] = atomicAdd(&cnt[g], 1u);   // ONE atomic: rank AND hist
                } else g_[k] = 0xFFFFFFFFu;
            }
            __syncthreads();

            unsigned int myc[4];
            unsigned int loc[4];
            unsigned int acc = 0;
#pragma unroll
            for (int j = 0; j < 4; ++j) {
                myc[j] = cnt[t * 4 + j];
                loc[j] = acc; acc += myc[j];
            }
            partial[t] = acc;
            __syncthreads();
            for (int d = 1; d < 256; d <<= 1) {
                unsigned int v = (t >= d) ? partial[t - d] : 0u;
                __syncthreads();
                partial[t] += v;
                __syncthreads();
            }
            unsigned int excl = (t > 0) ? partial[t - 1] : 0u;
            unsigned int myb[4];
#pragma unroll
            for (int j = 0; j < 4; ++j) {
                myb[j] = excl + loc[j];
                base_[t * 4 + j] = myb[j];
            }
            __syncthreads();

#pragma unroll
            for (int k = 0; k < CEPT; ++k) {
                if (g_[k] != 0xFFFFFFFFu) {
                    sorted[base_[g_[k]] + r_[k]] =
                        ((unsigned long long)q_[k].y << 32) | (unsigned long long)q_[k].x;
                }
            }
            __syncthreads();

#pragma unroll
            for (int j = 0; j < 4; ++j) {
                unsigned int bs = myb[j], c = myc[j];
                for (unsigned int p2 = bs; p2 < bs + c; ++p2) {
                    unsigned long long v = sorted[p2];
                    unsigned int lo = (unsigned int)v, hi = (unsigned int)(v >> 32);
                    a0[j] += __uint_as_float(lo << 16);
                    a1[j] += __uint_as_float(lo & 0xffff0000u);
                    a2[j] += __uint_as_float(hi << 16);
                    a3[j] += __uint_as_float(hi & 0xffff0000u);
                }
                an[j] += (float)c;
            }
            __syncthreads();
        }
    }

#pragma unroll
    for (int j = 0; j < 4; ++j) {
        int g = t * 4 + j;
        if (g >= GPB) continue;
        unsigned int G = b * GPB + (unsigned int)g;
        if (G >= N_GUN) continue;
        float inv = 1.0f / fmaxf(an[j], 1.0f);
        float m0 = a0[j] * inv, m1 = a1[j] * inv, m2 = a2[j] * inv, m3 = a3[j] * inv;
        float xv = xg[G];
        float res[OUTD];
#pragma unroll
        for (int o = 0; o < OUTD; ++o) {
            res[o] = m0 * sP[o] + m1 * sP[8 + o] + m2 * sP[16 + o] + m3 * sP[24 + o]
                   + xv * sP[32 + o] + sP[40 + o];
        }
        float4* op = (float4*)(out + (size_t)G * OUTD);
        op[0] = make_float4(res[0], res[1], res[2], res[3]);
        op[1] = make_float4(res[4], res[5], res[6], res[7]);
    }
}

// ================= atomic fallback (tiny ws) =================================
__global__ void edge_kernel(const int4* __restrict__ esrc4, const int4* __restrict__ edst4,
                            const float4* __restrict__ xe, float* __restrict__ summed,
                            float* __restrict__ counts) {
    int t = blockIdx.x * blockDim.x + threadIdx.x;
    if (t >= N_EDGES / 4) return;
    int4 s4 = esrc4[t];
    int4 d4 = edst4[t];
    int ss[4] = { s4.x, s4.y, s4.z, s4.w };
    int dd[4] = { d4.x, d4.y, d4.z, d4.w };
#pragma unroll
    for (int k = 0; k < 4; ++k) {
        float4 m = xe[ss[k]];
        float* basep = summed + (size_t)dd[k] * 4;
        atomicAdd(basep + 0, m.x);
        atomicAdd(basep + 1, m.y);
        atomicAdd(basep + 2, m.z);
        atomicAdd(basep + 3, m.w);
        atomicAdd(counts + dd[k], 1.0f);
    }
}

__global__ void gun_kernel(const float4* __restrict__ summed, const float* __restrict__ counts,
                           const float* __restrict__ xg, const float* __restrict__ P,
                           float* __restrict__ out) {
    __shared__ float sP[48];
    if (threadIdx.x < 48) sP[threadIdx.x] = P[threadIdx.x];
    __syncthreads();
    int g = blockIdx.x * blockDim.x + threadIdx.x;
    if (g >= N_GUN) return;
    float4 s = summed[g];
    float cnt = counts[g];
    float inv = 1.0f / fmaxf(cnt, 1.0f);
    float m0 = s.x * inv, m1 = s.y * inv, m2 = s.z * inv, m3 = s.w * inv;
    float xv = xg[g];
    float res[OUTD];
#pragma unroll
    for (int o = 0; o < OUTD; ++o) {
        res[o] = m0 * sP[o] + m1 * sP[8 + o] + m2 * sP[16 + o] + m3 * sP[24 + o]
               + xv * sP[32 + o] + sP[40 + o];
    }
    float4* op = (float4*)(out + (size_t)g * OUTD);
    op[0] = make_float4(res[0], res[1], res[2], res[3]);
    op[1] = make_float4(res[4], res[5], res[6], res[7]);
}

extern "C" void kernel_launch(void* const* d_in, const int* in_sizes, int n_in,
                              void* d_out, int out_size, void* d_ws, size_t ws_size,
                              hipStream_t stream) {
    const float* x_enemy = (const float*)d_in[0];
    const float* x_gun   = (const float*)d_in[1];
    const int*   esrc    = (const int*)d_in[2];
    const int*   edst    = (const int*)d_in[3];
    const float* W_l     = (const float*)d_in[4];
    const float* b_l     = (const float*)d_in[5];
    const float* W_r     = (const float*)d_in[6];
    const float* W_fc    = (const float*)d_in[7];
    const float* b_fc    = (const float*)d_in[8];
    float* out = (float*)d_out;

    // ws layout (u32 units). tileh (u16, 4MB) aliases the xeb region: tileh is
    // consumed by scatter_sorted; conv_kernel (writing xeb) runs after slice_sort.
    const size_t PAYLOAD_OFF = 0;                            // 16M u32 = 64 MB
    const size_t XEB_OFF     = (size_t)N_EDGES;              // 8M u32 = 32 MB
    const size_t TOT_OFF     = XEB_OFF + (size_t)N_ENEMY*2;  // +1024
    const size_t OFFS_OFF    = TOT_OFF + NB;                 // +1025
    const size_t P_OFF       = OFFS_OFF + NB + 1;            // +48
    const size_t STAB_OFF    = P_OFF + 48;                   // +NB*(NS+1)
    const size_t NEEDED_FULL = (STAB_OFF + (size_t)NB * (NS + 1) + 16) * sizeof(unsigned int);

    if (ws_size >= NEEDED_FULL) {
        unsigned int*   ws      = (unsigned int*)d_ws;
        unsigned int*   payload = ws + PAYLOAD_OFF;
        uint2*          xeb     = (uint2*)(ws + XEB_OFF);
        unsigned short* tileh   = (unsigned short*)(ws + XEB_OFF);  // alias, dead before conv
        unsigned int*   tot     = ws + TOT_OFF;
        unsigned int*   offsets = ws + OFFS_OFF;
        float*          P       = (float*)(ws + P_OFF);
        unsigned int*   stab    = ws + STAB_OFF;

        prep_params<<<1, 64, 0, stream>>>(W_l, b_l, W_r, W_fc, b_fc, P);
        hist2_kernel<<<NT8, 256, 0, stream>>>(edst, tileh);
        tile_scanT<8><<<NB / 16, 256, 0, stream>>>(tileh, tot, NB, NT8);
        scan_kernel<<<1, 1024, 0, stream>>>(tot, offsets);
        scatter_sorted<<<NT8, 256, 0, stream>>>(esrc, edst, offsets, tileh, payload);
        slice_sort<<<NB, 256, 0, stream>>>(offsets, payload, stab);
        conv_kernel<<<(N_ENEMY + 255) / 256, 256, 0, stream>>>((const uint4*)x_enemy, xeb);
        bucket_v9<<<NB, 256, 0, stream>>>(stab, payload, xeb, x_gun, P, out);
    } else {
        float* summed = (float*)d_ws;
        float* counts = summed + (size_t)N_GUN * 4;
        float* P      = counts + N_GUN;
        hipMemsetAsync(d_ws, 0, ((size_t)N_GUN * 5 + 48) * sizeof(float), stream);
        prep_params<<<1, 64, 0, stream>>>(W_l, b_l, W_r, W_fc, b_fc, P);
        int edge_threads = N_EDGES / 4;
        edge_kernel<<<(edge_threads + 255) / 256, 256, 0, stream>>>(
            (const int4*)esrc, (const int4*)edst, (const float4*)x_enemy, summed, counts);
        gun_kernel<<<(N_GUN + 255) / 256, 256, 0, stream>>>(
            (const float4*)summed, counts, x_gun, P, out);
    }
}